// Round 2
// baseline (781.184 us; speedup 1.0000x reference)
//
#include <hip/hip_runtime.h>
#include <hip/hip_bf16.h>

#define NHEADS 16
#define HDIM 4
#define NB 8
#define NHH 128
#define NWW 128
#define NTOK (NHH*NWW)       // 16384 tokens per batch
#define TOTTOK (NB*NTOK)     // 131072

typedef __hip_bfloat16 bf16;

__device__ __forceinline__ float b2f(bf16 v){ return __bfloat162float(v); }

// ---------------- FiLM pooling: te -> [B,1024] ----------------
__global__ __launch_bounds__(128) void pool_kernel(const float* __restrict__ te,
                                                   float* __restrict__ pool){
    // grid = B*C*16 = 8192; blk = b*1024 + c*16 + ph*4 + pw
    int blk = blockIdx.x;
    int region = blk & 15;
    int c = (blk >> 4) & 63;
    int b = blk >> 10;
    int ph = region >> 2, pw = region & 3;
    const float* base = te + ((size_t)(b*64 + c))*NTOK + (size_t)(ph*32)*NWW + pw*32;
    int t = threadIdx.x;
    float s = 0.f;
    #pragma unroll
    for (int j = 0; j < 8; ++j){
        int e = t + j*128;
        int i = e >> 5, w = e & 31;
        s += base[i*NWW + w];
    }
    for (int off = 32; off > 0; off >>= 1) s += __shfl_down(s, off, 64);
    __shared__ float tmp[2];
    if ((t & 63) == 0) tmp[t >> 6] = s;
    __syncthreads();
    if (t == 0) pool[blk] = (tmp[0] + tmp[1]) * (1.f/1024.f);
}

// ---------------- FiLM MLP: [B,1024] -> gb[B,128] ----------------
__global__ __launch_bounds__(128) void film_kernel(const float* __restrict__ pool,
        const float* __restrict__ m1w, const float* __restrict__ m1b,
        const float* __restrict__ m2w, const float* __restrict__ m2b,
        float* __restrict__ gb){
    int b = blockIdx.x; int j = threadIdx.x;
    __shared__ float tel[1024];
    __shared__ float hm[128];
    for (int i = j; i < 1024; i += 128) tel[i] = pool[b*1024 + i];
    __syncthreads();
    float s = m1b[j];
    for (int i = 0; i < 1024; ++i) s = fmaf(tel[i], m1w[i*128 + j], s);
    hm[j] = (s > 0.f) ? s : 0.01f*s;   // leaky_relu
    __syncthreads();
    float g = m2b[j];
    for (int i = 0; i < 128; ++i) g = fmaf(hm[i], m2w[i*128 + j], g);
    gb[b*128 + j] = g;
}

// ---------------- LN1 + Q/K/V projections ----------------
__global__ __launch_bounds__(256) void qkv_kernel(
    const float* __restrict__ x, const float* __restrict__ te,
    const float* __restrict__ qw, const float* __restrict__ qb,
    const float* __restrict__ kw, const float* __restrict__ kb,
    const float* __restrict__ vw, const float* __restrict__ vb,
    const float* __restrict__ ln1w, const float* __restrict__ ln1b,
    float* __restrict__ Q, float* __restrict__ K, float* __restrict__ V){
    __shared__ float wq[4096], wk[4096], wv[4096];
    __shared__ float bq[64], bk[64], bv[64], lw[64], lb[64];
    __shared__ float xp[32][66], pr[32][66];
    int tid = threadIdx.x;
    for (int i = tid; i < 4096; i += 256){ wq[i]=qw[i]; wk[i]=kw[i]; wv[i]=vw[i]; }
    if (tid < 64){ bq[tid]=qb[tid]; bk[tid]=kb[tid]; bv[tid]=vb[tid];
                   lw[tid]=ln1w[tid]; lb[tid]=ln1b[tid]; }
    int t0 = blockIdx.x * 32;
    int b = t0 >> 14;
    int n0 = t0 & (NTOK-1);
    const size_t basec = (size_t)b*64*NTOK + n0;
    for (int i = tid; i < 2048; i += 256){
        int c = i >> 5, j = i & 31;
        size_t a = basec + (size_t)c*NTOK + j;
        xp[j][c] = x[a];
        pr[j][c] = te[a];
    }
    __syncthreads();
    // LayerNorm on pr (8 threads per token)
    {
        int tl = tid >> 3, jj = tid & 7;
        float s=0.f, s2=0.f;
        #pragma unroll
        for (int u = 0; u < 8; ++u){ float v = pr[tl][jj*8+u]; s += v; s2 = fmaf(v,v,s2); }
        for (int off=1; off<8; off<<=1){ s += __shfl_xor(s, off, 8); s2 += __shfl_xor(s2, off, 8); }
        float mean = s * (1.f/64.f);
        float var  = s2 * (1.f/64.f) - mean*mean;
        float rstd = rsqrtf(var + 1e-5f);
        #pragma unroll
        for (int u = 0; u < 8; ++u){
            int c = jj*8+u;
            pr[tl][c] = (pr[tl][c]-mean)*rstd*lw[c] + lb[c];
        }
    }
    __syncthreads();
    int o = tid & 63, tg = tid >> 6;
    for (int g = 0; g < 8; ++g){
        int tok = g*4 + tg;
        float aq = bq[o], ak = bk[o], av = bv[o];
        #pragma unroll 8
        for (int c = 0; c < 64; ++c){
            float p = pr[tok][c], xx = xp[tok][c];
            aq = fmaf(p,  wq[c*64+o], aq);
            ak = fmaf(xx, wk[c*64+o], ak);
            av = fmaf(xx, wv[c*64+o], av);
        }
        size_t oa = (size_t)(t0+tok)*64 + o;
        Q[oa]=aq; K[oa]=ak; V[oa]=av;
    }
}

// ---------------- block-diagonal attention (chunk=128, 16 heads, hd=4) ----------------
// attnout aliases V: each block fully stages its own 128-token K/V chunk into LDS
// (before __syncthreads) and only then writes attn for those same tokens. NO __restrict__.
__global__ __launch_bounds__(256) void attn_kernel(
    const float* __restrict__ Q, const float* K, const float* V,
    float* attnout){
    __shared__ __align__(16) float Kl[128*64];
    __shared__ __align__(16) float Vl[128*64];
    int tid = threadIdx.x;
    size_t t0 = (size_t)blockIdx.x * 128;   // global chunk id * 128
    const float4* Ks = (const float4*)(K + t0*64);
    const float4* Vs = (const float4*)(V + t0*64);
    float4* K4 = (float4*)Kl; float4* V4 = (float4*)Vl;
    for (int i = tid; i < 2048; i += 256){ K4[i] = Ks[i]; V4[i] = Vs[i]; }
    __syncthreads();
    int lane = tid & 63, w = tid >> 6;
    for (int hh = 0; hh < 4; ++hh){
        int h4 = (w*4 + hh)*4;
        for (int qq = 0; qq < 2; ++qq){
            int q = qq*64 + lane;
            float4 qv = *(const float4*)(Q + (t0 + q)*64 + h4);
            // fold 1/sqrt(head_dim)=0.5 into q
            float q0=qv.x*0.5f, q1=qv.y*0.5f, q2=qv.z*0.5f, q3=qv.w*0.5f;
            float l=0.f, a0=0.f,a1=0.f,a2=0.f,a3=0.f;
            // scores ~ N(0, small): exp without max-subtraction is safe
            #pragma unroll 4
            for (int k = 0; k < 128; ++k){
                float4 kv = *(const float4*)&Kl[k*64 + h4];
                float s = q0*kv.x + q1*kv.y + q2*kv.z + q3*kv.w;
                float p = __expf(s);
                l += p;
                float4 vv = *(const float4*)&Vl[k*64 + h4];
                a0 = fmaf(p, vv.x, a0); a1 = fmaf(p, vv.y, a1);
                a2 = fmaf(p, vv.z, a2); a3 = fmaf(p, vv.w, a3);
            }
            float inv = 1.f / l;
            float4 ov; ov.x=a0*inv; ov.y=a1*inv; ov.z=a2*inv; ov.w=a3*inv;
            *(float4*)(attnout + (t0+q)*64 + h4) = ov;
        }
    }
}

// ---------------- attn @ o_w + o_b + prior residual -> h ----------------
// h aliases attn (in-place): block stages its 32 tokens of attn into LDS before
// __syncthreads, writes h for the same tokens after. NO __restrict__ on those.
__global__ __launch_bounds__(256) void oproj_kernel(
    const float* attn, const float* __restrict__ te,
    const float* __restrict__ ow, const float* __restrict__ ob,
    float* h){
    __shared__ float wo[4096]; __shared__ float bo[64];
    __shared__ float at[32][66]; __shared__ float pr[32][66];
    int tid = threadIdx.x;
    for (int i = tid; i < 4096; i += 256) wo[i] = ow[i];
    if (tid < 64) bo[tid] = ob[tid];
    int t0 = blockIdx.x*32;
    int b = t0 >> 14, n0 = t0 & (NTOK-1);
    const size_t basec = (size_t)b*64*NTOK + n0;
    for (int i = tid; i < 2048; i += 256){
        int tok = i >> 6, c = i & 63;
        at[tok][c] = attn[(size_t)(t0+tok)*64 + c];
    }
    for (int i = tid; i < 2048; i += 256){
        int c = i >> 5, j = i & 31;
        pr[j][c] = te[basec + (size_t)c*NTOK + j];
    }
    __syncthreads();
    int o = tid & 63, tg = tid >> 6;
    for (int g = 0; g < 8; ++g){
        int tok = g*4 + tg;
        float acc = bo[o];
        #pragma unroll 8
        for (int c = 0; c < 64; ++c) acc = fmaf(at[tok][c], wo[c*64+o], acc);
        acc += pr[tok][o];
        h[(size_t)(t0+tok)*64 + o] = acc;
    }
}

// ---------------- LN2 + fc1 + exact GELU -> hidden (bf16) ----------------
__global__ __launch_bounds__(256) void fc1_kernel(
    const float* __restrict__ h, const float* __restrict__ ln2w, const float* __restrict__ ln2b,
    const float* __restrict__ w1, const float* __restrict__ b1,
    bf16* __restrict__ hid){
    __shared__ __align__(16) float wl[64*256];   // [c][o]
    __shared__ float bl[256], lw[64], lb[64];
    __shared__ float hn[32][66];
    int tid = threadIdx.x;
    for (int i = tid; i < 16384; i += 256) wl[i] = w1[i];
    bl[tid] = b1[tid];
    if (tid < 64){ lw[tid]=ln2w[tid]; lb[tid]=ln2b[tid]; }
    int t0 = blockIdx.x*32;
    for (int i = tid; i < 2048; i += 256){
        int tok = i >> 6, c = i & 63;
        hn[tok][c] = h[(size_t)(t0+tok)*64 + c];
    }
    __syncthreads();
    {   // LN2 in place
        int tl = tid >> 3, jj = tid & 7;
        float s=0.f,s2=0.f;
        #pragma unroll
        for (int u=0;u<8;++u){ float v=hn[tl][jj*8+u]; s+=v; s2=fmaf(v,v,s2); }
        for (int off=1;off<8;off<<=1){ s+=__shfl_xor(s,off,8); s2+=__shfl_xor(s2,off,8); }
        float mean = s*(1.f/64.f);
        float var  = s2*(1.f/64.f)-mean*mean;
        float rstd = rsqrtf(var+1e-5f);
        #pragma unroll
        for (int u=0;u<8;++u){ int c=jj*8+u; hn[tl][c]=(hn[tl][c]-mean)*rstd*lw[c]+lb[c]; }
    }
    __syncthreads();
    // 8 tokens x 4 outputs per thread
    int o = tid & 63, tg = tid >> 6;
    int tb = tg*8;
    float acc[8][4];
    #pragma unroll
    for (int u=0;u<8;++u){
        acc[u][0]=bl[o]; acc[u][1]=bl[o+64]; acc[u][2]=bl[o+128]; acc[u][3]=bl[o+192];
    }
    for (int c = 0; c < 64; ++c){
        float w0 = wl[c*256+o], wa = wl[c*256+o+64], wb = wl[c*256+o+128], wc = wl[c*256+o+192];
        #pragma unroll
        for (int u = 0; u < 8; ++u){
            float hv = hn[tb+u][c];
            acc[u][0] = fmaf(hv, w0, acc[u][0]);
            acc[u][1] = fmaf(hv, wa, acc[u][1]);
            acc[u][2] = fmaf(hv, wb, acc[u][2]);
            acc[u][3] = fmaf(hv, wc, acc[u][3]);
        }
    }
    for (int u=0;u<8;++u){
        size_t base = (size_t)(t0+tb+u)*256 + o;
        #pragma unroll
        for (int v=0;v<4;++v){
            float xv = acc[u][v];
            float g = 0.5f*xv*(1.f + erff(xv*0.70710678118654752f)); // exact GELU
            hid[base + v*64] = __float2bfloat16(g);
        }
    }
}

// ---------------- fc2 + residual -> h2 (in place over h) ----------------
// h2 aliases h: each (token, o4) slot is read (residual) and written by the SAME thread.
__global__ __launch_bounds__(256) void fc2_kernel(
    const bf16* __restrict__ hid,
    const float* __restrict__ w2, const float* __restrict__ b2,
    float* h2){
    __shared__ __align__(16) bf16 wl[256*64];   // [c][o], bf16 to fit 2 blocks/CU
    __shared__ float bl[64];
    __shared__ float hidt[32][258];
    int tid = threadIdx.x;
    for (int i = tid; i < 16384; i += 256) wl[i] = __float2bfloat16(w2[i]);
    if (tid < 64) bl[tid] = b2[tid];
    int t0 = blockIdx.x*32;
    for (int i = tid; i < 8192; i += 256){
        int tok = i >> 8, c = i & 255;
        hidt[tok][c] = b2f(hid[(size_t)(t0+tok)*256 + c]);
    }
    __syncthreads();
    int o4 = (tid & 15)*4;
    int tp = (tid >> 4)*2;      // 2 tokens x 4 outputs per thread
    float acc0[4], acc1[4];
    #pragma unroll
    for (int v=0;v<4;++v){ acc0[v]=bl[o4+v]; acc1[v]=bl[o4+v]; }
    for (int c = 0; c < 256; ++c){
        const __hip_bfloat162* wp = (const __hip_bfloat162*)&wl[c*64 + o4];
        float2 wa = __bfloat1622float2(wp[0]);
        float2 wb = __bfloat1622float2(wp[1]);
        float h0 = hidt[tp][c], h1 = hidt[tp+1][c];
        acc0[0]=fmaf(h0,wa.x,acc0[0]); acc0[1]=fmaf(h0,wa.y,acc0[1]);
        acc0[2]=fmaf(h0,wb.x,acc0[2]); acc0[3]=fmaf(h0,wb.y,acc0[3]);
        acc1[0]=fmaf(h1,wa.x,acc1[0]); acc1[1]=fmaf(h1,wa.y,acc1[1]);
        acc1[2]=fmaf(h1,wb.x,acc1[2]); acc1[3]=fmaf(h1,wb.y,acc1[3]);
    }
    size_t a0 = (size_t)(t0+tp)*64 + o4;
    size_t a1 = (size_t)(t0+tp+1)*64 + o4;
    float4 r0 = *(const float4*)&h2[a0];   // old h (residual), same-thread RAW
    float4 r1 = *(const float4*)&h2[a1];
    float4 s0, s1;
    s0.x=acc0[0]+r0.x; s0.y=acc0[1]+r0.y; s0.z=acc0[2]+r0.z; s0.w=acc0[3]+r0.w;
    s1.x=acc1[0]+r1.x; s1.y=acc1[1]+r1.y; s1.z=acc1[2]+r1.z; s1.w=acc1[3]+r1.w;
    *(float4*)&h2[a0] = s0;
    *(float4*)&h2[a1] = s1;
}

// ---------------- 1x1 conv + x residual + FiLM -> out (fp32, [B,C,H,W]) ----------------
__global__ __launch_bounds__(256) void conv_kernel(
    const float* __restrict__ h2, const float* __restrict__ x,
    const float* __restrict__ cw, const float* __restrict__ cb,
    const float* __restrict__ gb, float* __restrict__ out){
    __shared__ float wl[4096];    // conv_w [o][i]
    __shared__ float bl[64];
    __shared__ float h2t[64][66];
    int tid = threadIdx.x;
    for (int i = tid; i < 4096; i += 256) wl[i] = cw[i];
    if (tid < 64) bl[tid] = cb[tid];
    int t0 = blockIdx.x*64;
    int b = t0 >> 14, n0 = t0 & (NTOK-1);
    for (int i = tid; i < 4096; i += 256){
        int tok = i >> 6, c = i & 63;
        h2t[tok][c] = h2[(size_t)(t0+tok)*64 + c];
    }
    __syncthreads();
    int j = tid & 63;     // token within tile (coalesced n)
    int cg = tid >> 6;    // wave -> channel group
    const size_t bbase = (size_t)b*64*NTOK + n0 + j;
    for (int u = 0; u < 16; ++u){
        int c = cg + u*4;
        float acc = bl[c];
        #pragma unroll 8
        for (int i2 = 0; i2 < 64; ++i2)
            acc = fmaf(h2t[j][i2], wl[c*64+i2], acc);
        size_t a = bbase + (size_t)c*NTOK;
        acc += x[a];                            // conv + x
        float gamma = gb[b*128 + c], beta = gb[b*128 + 64 + c];
        out[a] = fmaf(1.f+gamma, acc, beta);
    }
}

extern "C" void kernel_launch(void* const* d_in, const int* in_sizes, int n_in,
                              void* d_out, int out_size, void* d_ws, size_t ws_size,
                              hipStream_t stream){
    const float* x   = (const float*)d_in[0];
    const float* te  = (const float*)d_in[1];
    const float* qw  = (const float*)d_in[2];
    const float* qb  = (const float*)d_in[3];
    const float* kw  = (const float*)d_in[4];
    const float* kb  = (const float*)d_in[5];
    const float* vw  = (const float*)d_in[6];
    const float* vb  = (const float*)d_in[7];
    const float* ow  = (const float*)d_in[8];
    const float* ob  = (const float*)d_in[9];
    const float* ln1w= (const float*)d_in[10];
    const float* ln1b= (const float*)d_in[11];
    const float* ln2w= (const float*)d_in[12];
    const float* ln2b= (const float*)d_in[13];
    const float* w1  = (const float*)d_in[14];
    const float* b1  = (const float*)d_in[15];
    const float* w2  = (const float*)d_in[16];
    const float* b2  = (const float*)d_in[17];
    const float* cw  = (const float*)d_in[18];
    const float* cb  = (const float*)d_in[19];
    const float* m1w = (const float*)d_in[20];
    const float* m1b = (const float*)d_in[21];
    const float* m2w = (const float*)d_in[22];
    const float* m2b = (const float*)d_in[23];

    char* ws = (char*)d_ws;
    const size_t BUF = (size_t)TOTTOK*64*4;       // 33.55 MB per fp32 buffer
    float* Q    = (float*)(ws);
    float* K    = (float*)(ws + BUF);
    float* V    = (float*)(ws + 2*BUF);
    // aliases (all in-place, block-local token ranges):
    float* attn = V;                              // attn overwrites V
    float* hbuf = V;                              // h overwrites attn
    bf16*  hid  = (bf16*)(ws);                    // hid (bf16, 67MB) over dead Q+K
    float* h2   = V;                              // h2 overwrites h
    float* pool = (float*)(ws + 3*BUF);
    float* gbp  = (float*)(ws + 3*BUF + 32768);
    // total ws usage: 3*BUF + 36 KB ~= 100.7 MB

    pool_kernel<<<8192, 128, 0, stream>>>(te, pool);
    film_kernel<<<8, 128, 0, stream>>>(pool, m1w, m1b, m2w, m2b, gbp);
    qkv_kernel<<<TOTTOK/32, 256, 0, stream>>>(x, te, qw, qb, kw, kb, vw, vb, ln1w, ln1b, Q, K, V);
    attn_kernel<<<TOTTOK/128, 256, 0, stream>>>(Q, K, V, attn);
    oproj_kernel<<<TOTTOK/32, 256, 0, stream>>>(attn, te, ow, ob, hbuf);
    fc1_kernel<<<TOTTOK/32, 256, 0, stream>>>(hbuf, ln2w, ln2b, w1, b1, hid);
    fc2_kernel<<<TOTTOK/32, 256, 0, stream>>>(hid, w2, b2, h2);
    conv_kernel<<<TOTTOK/64, 256, 0, stream>>>(h2, x, cw, cb, gbp, (float*)d_out);
}

// Round 3
// 423.665 us; speedup vs baseline: 1.8439x; 1.8439x over previous
//
#include <hip/hip_runtime.h>
#include <hip/hip_bf16.h>

#define NB 8
#define NTOK 16384           // tokens per batch (128*128)
#define TOTTOK (NB*NTOK)     // 131072

typedef __hip_bfloat16 bf16;
typedef __attribute__((ext_vector_type(8))) short bfrag;   // 8 bf16 = 4 VGPR
typedef __attribute__((ext_vector_type(4))) float ffrag;   // 4 fp32 acc

#define MFMA(a,b,c) __builtin_amdgcn_mfma_f32_16x16x32_bf16(a,b,c,0,0,0)

__device__ __forceinline__ float b2f(bf16 v){ return __bfloat162float(v); }
__device__ __forceinline__ bf16 f2b(float v){ return __float2bfloat16(v); }
__device__ __forceinline__ float bfu(unsigned short u){
    union { float f; unsigned v; } x; x.v = ((unsigned)u) << 16; return x.f; }
// load 4 consecutive bf16 (8B aligned) -> 4 floats
__device__ __forceinline__ void ld4(const bf16* p, float* f){
    uint2 r = *(const uint2*)p;
    f[0]=bfu(r.x & 0xffff); f[1]=bfu(r.x >> 16); f[2]=bfu(r.y & 0xffff); f[3]=bfu(r.y >> 16);
}
// A/B fragment load: matrix row-major [rows][K], p points at [tile_row0][k0].
// lane L: row += L&15, k += (L>>4)*8  (A: row=m; B: row=n, from W^T storage)
__device__ __forceinline__ bfrag ld_frag(const bf16* p, int stride){
    int lane = threadIdx.x & 63;
    return *(const bfrag*)(p + (lane & 15)*stride + (lane >> 4)*8);
}

// ---------------- FiLM pooling: te -> [B,1024] ----------------
__global__ __launch_bounds__(128) void pool_kernel(const float* __restrict__ te,
                                                   float* __restrict__ pool){
    int blk = blockIdx.x;              // b*1024 + c*16 + ph*4 + pw
    int region = blk & 15;
    int c = (blk >> 4) & 63;
    int b = blk >> 10;
    int ph = region >> 2, pw = region & 3;
    const float* base = te + ((size_t)(b*64 + c))*NTOK + (size_t)(ph*32)*128 + pw*32;
    int t = threadIdx.x;
    float s = 0.f;
    #pragma unroll
    for (int j = 0; j < 8; ++j){
        int e = t + j*128;
        int i = e >> 5, w = e & 31;
        s += base[i*128 + w];
    }
    for (int off = 32; off > 0; off >>= 1) s += __shfl_down(s, off, 64);
    __shared__ float tmp[2];
    if ((t & 63) == 0) tmp[t >> 6] = s;
    __syncthreads();
    if (t == 0) pool[blk] = (tmp[0] + tmp[1]) * (1.f/1024.f);
}

// ---------------- FiLM MLP: [B,1024] -> gb[B,128] ----------------
__global__ __launch_bounds__(128) void film_kernel(const float* __restrict__ pool,
        const float* __restrict__ m1w, const float* __restrict__ m1b,
        const float* __restrict__ m2w, const float* __restrict__ m2b,
        float* __restrict__ gb){
    int b = blockIdx.x; int j = threadIdx.x;
    __shared__ float tel[1024];
    __shared__ float hm[128];
    for (int i = j; i < 1024; i += 128) tel[i] = pool[b*1024 + i];
    __syncthreads();
    float s = m1b[j];
    for (int i = 0; i < 1024; ++i) s = fmaf(tel[i], m1w[i*128 + j], s);
    hm[j] = (s > 0.f) ? s : 0.01f*s;
    __syncthreads();
    float g = m2b[j];
    for (int i = 0; i < 128; ++i) g = fmaf(hm[i], m2w[i*128 + j], g);
    gb[b*128 + j] = g;
}

// ---------------- LN1 + QKV (MFMA) -> Q,K,V bf16 [tok][64] ----------------
__global__ __launch_bounds__(256,2) void qkv_kernel(
    const float* __restrict__ x, const float* __restrict__ te,
    const float* __restrict__ qw, const float* __restrict__ qb,
    const float* __restrict__ kw, const float* __restrict__ kb_,
    const float* __restrict__ vw, const float* __restrict__ vb,
    const float* __restrict__ ln1w, const float* __restrict__ ln1b,
    bf16* __restrict__ Qg, bf16* __restrict__ Kg, bf16* __restrict__ Vg)
{
    __shared__ __align__(16) bf16 PN[128*64];     // te tile -> prior_norm ; then Q out
    __shared__ __align__(16) bf16 XT[128*64];     // x tile ; then K out
    __shared__ __align__(16) bf16 WT[3*64*72];    // wq^T,wk^T,wv^T (stride 72) ; then V out
    __shared__ float bias[192];
    __shared__ float lnw[64], lnb[64];
    int tid = threadIdx.x;
    int t0 = blockIdx.x * 128;
    int b = t0 >> 14, n0 = t0 & (NTOK-1);
    const size_t basec = (size_t)b*64*NTOK + n0;
    // stage te,x: global [c][j] (coalesced) -> LDS [j][c] bf16
    for (int i = tid; i < 8192; i += 256){
        int c = i >> 7, j = i & 127;
        size_t a = basec + (size_t)c*NTOK + j;
        PN[j*64 + c] = f2b(te[a]);
        XT[j*64 + c] = f2b(x[a]);
    }
    // stage weights transposed: w[i][o] -> WT[o*72 + i]
    for (int i = tid; i < 4096; i += 256){
        int ii = i >> 6, o = i & 63;
        WT[o*72 + ii]           = f2b(qw[i]);
        WT[4608 + o*72 + ii]    = f2b(kw[i]);
        WT[9216 + o*72 + ii]    = f2b(vw[i]);
    }
    if (tid < 64){ bias[tid]=qb[tid]; bias[64+tid]=kb_[tid]; bias[128+tid]=vb[tid];
                   lnw[tid]=ln1w[tid]; lnb[tid]=ln1b[tid]; }
    __syncthreads();
    // LN1 in place on PN: 2 threads (adjacent lanes) per token
    {
        int tok = tid >> 1, half = (tid & 1)*32;
        float vb_[32];
        float s = 0.f, s2 = 0.f;
        #pragma unroll
        for (int u = 0; u < 32; ++u){
            float v = b2f(PN[tok*64 + half + u]);
            vb_[u] = v; s += v; s2 = fmaf(v, v, s2);
        }
        s  += __shfl_xor(s, 1, 64);
        s2 += __shfl_xor(s2, 1, 64);
        float mean = s * (1.f/64.f);
        float var  = s2 * (1.f/64.f) - mean*mean;
        float rstd = rsqrtf(var + 1e-5f);
        #pragma unroll
        for (int u = 0; u < 32; ++u){
            int c = half + u;
            PN[tok*64 + c] = f2b((vb_[u]-mean)*rstd*lnw[c] + lnb[c]);
        }
    }
    __syncthreads();
    // MFMA: wave w owns m-tiles {2w, 2w+1}
    int w = tid >> 6, lane = tid & 63;
    ffrag accQ[2][4], accK[2][4], accV[2][4];
    #pragma unroll
    for (int mi=0;mi<2;++mi) for (int nt=0;nt<4;++nt){
        ffrag z = {0.f,0.f,0.f,0.f};
        accQ[mi][nt]=z; accK[mi][nt]=z; accV[mi][nt]=z;
    }
    bfrag aQ[2][2], aX[2][2];
    #pragma unroll
    for (int mi=0;mi<2;++mi) for (int kb2=0;kb2<2;++kb2){
        aQ[mi][kb2] = ld_frag(PN + (w*32 + mi*16)*64 + kb2*32, 64);
        aX[mi][kb2] = ld_frag(XT + (w*32 + mi*16)*64 + kb2*32, 64);
    }
    for (int nt = 0; nt < 4; ++nt){
        #pragma unroll
        for (int kb2 = 0; kb2 < 2; ++kb2){
            bfrag bq2 = ld_frag(WT +        nt*16*72 + kb2*32, 72);
            bfrag bk2 = ld_frag(WT + 4608 + nt*16*72 + kb2*32, 72);
            bfrag bv2 = ld_frag(WT + 9216 + nt*16*72 + kb2*32, 72);
            #pragma unroll
            for (int mi=0;mi<2;++mi){
                accQ[mi][nt] = MFMA(aQ[mi][kb2], bq2, accQ[mi][nt]);
                accK[mi][nt] = MFMA(aX[mi][kb2], bk2, accK[mi][nt]);
                accV[mi][nt] = MFMA(aX[mi][kb2], bv2, accV[mi][nt]);
            }
        }
    }
    __syncthreads();   // all frag reads done; slots become outputs
    int col = lane & 15, rq = (lane >> 4)*4;
    #pragma unroll
    for (int mi=0;mi<2;++mi) for (int nt=0;nt<4;++nt){
        int n = nt*16 + col;
        float bq3 = bias[n], bk3 = bias[64+n], bv3 = bias[128+n];
        #pragma unroll
        for (int r=0;r<4;++r){
            int m = w*32 + mi*16 + rq + r;
            PN[m*64 + n] = f2b(accQ[mi][nt][r] + bq3);
            XT[m*64 + n] = f2b(accK[mi][nt][r] + bk3);
            WT[m*64 + n] = f2b(accV[mi][nt][r] + bv3);
        }
    }
    __syncthreads();
    // coalesced copy to global bf16 [tok][64]
    uint2* gq = (uint2*)(Qg + (size_t)t0*64);
    uint2* gk = (uint2*)(Kg + (size_t)t0*64);
    uint2* gv = (uint2*)(Vg + (size_t)t0*64);
    for (int i = tid; i < 2048; i += 256){
        gq[i] = ((const uint2*)PN)[i];
        gk[i] = ((const uint2*)XT)[i];
        gv[i] = ((const uint2*)WT)[i];
    }
}

// ---------------- attention (VALU) + o-proj (MFMA) -> h' bf16 (no residual) ----------------
__global__ __launch_bounds__(256,2) void attn_oproj_kernel(
    const bf16* __restrict__ Qg, const bf16* __restrict__ Kg, const bf16* __restrict__ Vg,
    const float* __restrict__ ow, const float* __restrict__ ob,
    bf16* __restrict__ hout)
{
    __shared__ __align__(16) bf16 QL[128*72];
    __shared__ __align__(16) bf16 KL[128*64];   // later: h' out
    __shared__ __align__(16) bf16 VL[128*64];
    __shared__ __align__(16) bf16 AT[128*72];
    __shared__ __align__(16) bf16 OWT[64*72];
    __shared__ float bo[64];
    int tid = threadIdx.x;
    size_t t0 = (size_t)blockIdx.x * 128;
    for (int i = tid; i < 2048; i += 256){      // uint2 = 4 bf16
        int m = i >> 4, n4 = (i & 15)*4;
        *(uint2*)(QL + m*72 + n4) = ((const uint2*)(Qg + t0*64))[i];
        ((uint2*)KL)[i] = ((const uint2*)(Kg + t0*64))[i];
        ((uint2*)VL)[i] = ((const uint2*)(Vg + t0*64))[i];
    }
    for (int i = tid; i < 4096; i += 256){
        int ii = i >> 6, o = i & 63;
        OWT[o*72 + ii] = f2b(ow[i]);
    }
    if (tid < 64) bo[tid] = ob[tid];
    __syncthreads();
    int lane = tid & 63, w = tid >> 6;
    for (int hh = 0; hh < 4; ++hh){
        int h4 = (w*4 + hh)*4;                  // channel base = head*4
        float q0[4], q1[4];
        ld4(QL + lane*72 + h4, q0);
        ld4(QL + (lane+64)*72 + h4, q1);
        #pragma unroll
        for (int d=0;d<4;++d){ q0[d]*=0.5f; q1[d]*=0.5f; }   // /sqrt(head_dim)
        float l0=0.f,l1=0.f, a0[4]={0,0,0,0}, a1[4]={0,0,0,0};
        for (int k = 0; k < 128; ++k){
            float kv[4], vv[4];
            ld4(KL + k*64 + h4, kv);
            float s0 = q0[0]*kv[0]+q0[1]*kv[1]+q0[2]*kv[2]+q0[3]*kv[3];
            float s1 = q1[0]*kv[0]+q1[1]*kv[1]+q1[2]*kv[2]+q1[3]*kv[3];
            float p0 = __expf(s0), p1 = __expf(s1);
            l0 += p0; l1 += p1;
            ld4(VL + k*64 + h4, vv);
            #pragma unroll
            for (int d=0;d<4;++d){ a0[d]=fmaf(p0,vv[d],a0[d]); a1[d]=fmaf(p1,vv[d],a1[d]); }
        }
        float i0 = 1.f/l0, i1 = 1.f/l1;
        #pragma unroll
        for (int d=0;d<4;++d){
            AT[lane*72 + h4 + d]      = f2b(a0[d]*i0);
            AT[(lane+64)*72 + h4 + d] = f2b(a1[d]*i1);
        }
    }
    __syncthreads();
    // o-proj: D = AT @ OWT^T ; D -> KL slot
    ffrag acc[2][4];
    #pragma unroll
    for (int mi=0;mi<2;++mi) for (int nt=0;nt<4;++nt){ ffrag z={0.f,0.f,0.f,0.f}; acc[mi][nt]=z; }
    bfrag af[2][2];
    #pragma unroll
    for (int mi=0;mi<2;++mi) for (int kb2=0;kb2<2;++kb2)
        af[mi][kb2] = ld_frag(AT + (w*32 + mi*16)*72 + kb2*32, 72);
    for (int nt=0;nt<4;++nt){
        #pragma unroll
        for (int kb2=0;kb2<2;++kb2){
            bfrag bf_ = ld_frag(OWT + nt*16*72 + kb2*32, 72);
            #pragma unroll
            for (int mi=0;mi<2;++mi) acc[mi][nt] = MFMA(af[mi][kb2], bf_, acc[mi][nt]);
        }
    }
    int col = lane & 15, rq = (lane >> 4)*4;
    #pragma unroll
    for (int mi=0;mi<2;++mi) for (int nt=0;nt<4;++nt){
        int n = nt*16 + col;
        #pragma unroll
        for (int r=0;r<4;++r){
            int m = w*32 + mi*16 + rq + r;
            KL[m*64 + n] = f2b(acc[mi][nt][r] + bo[n]);
        }
    }
    __syncthreads();
    uint2* gh = (uint2*)(hout + t0*64);
    for (int i = tid; i < 2048; i += 256) gh[i] = ((const uint2*)KL)[i];
}

// ---------------- h'+te residual, LN2, fc1+GELU, fc2+residual, conv, FiLM -> out ----------------
__global__ __launch_bounds__(256,2) void ffn_conv_kernel(
    const bf16* __restrict__ hg, const float* __restrict__ te, const float* __restrict__ x,
    const float* __restrict__ ln2w, const float* __restrict__ ln2b,
    const float* __restrict__ w1, const float* __restrict__ b1,
    const float* __restrict__ w2, const float* __restrict__ b2,
    const float* __restrict__ cw, const float* __restrict__ cb,
    const float* __restrict__ gb, float* __restrict__ out)
{
    // hand-packed LDS = exactly 80 KB -> 2 blocks/CU
    __shared__ float sb1[256];
    __shared__ float sb2[64], slw[64], slb[64], scb[64], sg[64], sbt[64];
    __shared__ __align__(16) bf16 W2T[64*264];  // w2^T [o][k], stride 264
    __shared__ __align__(16) bf16 H[128*64];    // h ; later OT [c][tok] (conv out)
    __shared__ __align__(16) bf16 HN[128*64];   // te stage -> h_norm -> h2
    __shared__ __align__(16) bf16 WP[6400];     // W1S (2304) + P (4096) ; later convW [64][72]
    bf16* W1S = WP;            // [32][72] current w1 group^T
    bf16* P   = WP + 2304;     // [128][32] gelu(fc1 group)
    bf16* CWs = WP;            // [64][72] conv weights (after fc2)
    int tid = threadIdx.x;
    int t0 = blockIdx.x * 128;
    int b = t0 >> 14, n0 = t0 & (NTOK-1);
    const size_t basec = (size_t)b*64*NTOK + n0;
    // stage: h' -> H, te -> HN (transposed), w2^T, biases
    {
        const uint2* ghp = (const uint2*)(hg + (size_t)t0*64);
        for (int i = tid; i < 2048; i += 256) ((uint2*)H)[i] = ghp[i];
    }
    for (int i = tid; i < 8192; i += 256){
        int c = i >> 7, j = i & 127;
        HN[j*64 + c] = f2b(te[basec + (size_t)c*NTOK + j]);
    }
    for (int i = tid; i < 16384; i += 256){
        int k = i >> 6, o = i & 63;
        W2T[o*264 + k] = f2b(w2[i]);
    }
    if (tid < 64){ sb2[tid]=b2[tid]; slw[tid]=ln2w[tid]; slb[tid]=ln2b[tid];
                   scb[tid]=cb[tid]; sg[tid]=gb[b*128+tid]; sbt[tid]=gb[b*128+64+tid]; }
    sb1[tid] = b1[tid];
    __syncthreads();
    // h = h' + prior
    for (int i = tid; i < 8192; i += 256) H[i] = f2b(b2f(H[i]) + b2f(HN[i]));
    __syncthreads();
    // LN2: H -> HN
    {
        int tok = tid >> 1, half = (tid & 1)*32;
        float vb_[32];
        float s = 0.f, s2 = 0.f;
        #pragma unroll
        for (int u = 0; u < 32; ++u){
            float v = b2f(H[tok*64 + half + u]);
            vb_[u] = v; s += v; s2 = fmaf(v, v, s2);
        }
        s  += __shfl_xor(s, 1, 64);
        s2 += __shfl_xor(s2, 1, 64);
        float mean = s * (1.f/64.f);
        float var  = s2 * (1.f/64.f) - mean*mean;
        float rstd = rsqrtf(var + 1e-5f);
        #pragma unroll
        for (int u = 0; u < 32; ++u){
            int c = half + u;
            HN[tok*64 + c] = f2b((vb_[u]-mean)*rstd*slw[c] + slb[c]);
        }
    }
    __syncthreads();
    int w = tid >> 6, lane = tid & 63;
    int col = lane & 15, rq = (lane >> 4)*4;
    bfrag af[2][2];
    #pragma unroll
    for (int mi=0;mi<2;++mi) for (int kb2=0;kb2<2;++kb2)
        af[mi][kb2] = ld_frag(HN + (w*32 + mi*16)*64 + kb2*32, 64);
    ffrag acc2[2][4];
    #pragma unroll
    for (int mi=0;mi<2;++mi) for (int nt=0;nt<4;++nt){ ffrag z={0.f,0.f,0.f,0.f}; acc2[mi][nt]=z; }
    // 8 groups of 32 hidden channels: fc1 -> gelu -> P -> fc2 accumulate
    for (int g = 0; g < 8; ++g){
        __syncthreads();   // W1S reuse + P reuse safe
        for (int i = tid; i < 2048; i += 256){
            int ol = i & 31, ii = i >> 5;
            W1S[ol*72 + ii] = f2b(w1[ii*256 + g*32 + ol]);
        }
        __syncthreads();
        ffrag accg[2][2];
        #pragma unroll
        for (int mi=0;mi<2;++mi) for (int ntl=0;ntl<2;++ntl){ ffrag z={0.f,0.f,0.f,0.f}; accg[mi][ntl]=z; }
        #pragma unroll
        for (int ntl=0;ntl<2;++ntl)
            #pragma unroll
            for (int kb2=0;kb2<2;++kb2){
                bfrag bf_ = ld_frag(W1S + ntl*16*72 + kb2*32, 72);
                #pragma unroll
                for (int mi=0;mi<2;++mi) accg[mi][ntl] = MFMA(af[mi][kb2], bf_, accg[mi][ntl]);
            }
        // gelu -> P (each wave writes/readbacks only its own 32 rows: no barrier needed)
        #pragma unroll
        for (int mi=0;mi<2;++mi) for (int ntl=0;ntl<2;++ntl){
            int n = ntl*16 + col;
            float bb = sb1[g*32 + n];
            #pragma unroll
            for (int r=0;r<4;++r){
                int m = w*32 + mi*16 + rq + r;
                float xv = accg[mi][ntl][r] + bb;
                P[m*32 + n] = f2b(0.5f*xv*(1.f + erff(xv*0.70710678118654752f)));
            }
        }
        // fc2 partial: K-chunk g
        #pragma unroll
        for (int mi=0;mi<2;++mi){
            bfrag ap = ld_frag(P + (w*32 + mi*16)*32, 32);
            #pragma unroll
            for (int nt=0;nt<4;++nt){
                bfrag bf2 = ld_frag(W2T + nt*16*264 + g*32, 264);
                acc2[mi][nt] = MFMA(ap, bf2, acc2[mi][nt]);
            }
        }
    }
    __syncthreads();
    // h2 = fc2 + b2 + h -> HN ; stage conv weights -> CWs
    #pragma unroll
    for (int mi=0;mi<2;++mi) for (int nt=0;nt<4;++nt){
        int n = nt*16 + col;
        #pragma unroll
        for (int r=0;r<4;++r){
            int m = w*32 + mi*16 + rq + r;
            HN[m*64 + n] = f2b(acc2[mi][nt][r] + sb2[n] + b2f(H[m*64 + n]));
        }
    }
    for (int i = tid; i < 4096; i += 256){
        int c = i >> 6, ii = i & 63;
        CWs[c*72 + ii] = f2b(cw[i]);      // cw is [out][in] already
    }
    __syncthreads();
    // conv: D[c][tok] = CW[c][i] * h2[tok][i] ; wave w owns c-tile w
    bf16* OT = H;  // [64][128]
    {
        bfrag ac[2];
        #pragma unroll
        for (int kb2=0;kb2<2;++kb2) ac[kb2] = ld_frag(CWs + w*16*72 + kb2*32, 72);
        for (int nt = 0; nt < 8; ++nt){
            ffrag accc = {0.f,0.f,0.f,0.f};
            #pragma unroll
            for (int kb2=0;kb2<2;++kb2){
                bfrag bh = ld_frag(HN + nt*16*64 + kb2*32, 64);
                accc = MFMA(ac[kb2], bh, accc);
            }
            int tok = nt*16 + col;
            #pragma unroll
            for (int r=0;r<4;++r){
                int c = w*16 + rq + r;
                OT[c*128 + tok] = f2b(accc[r] + scb[c]);
            }
        }
    }
    __syncthreads();
    // out = (1+gamma)*(conv + x) + beta, coalesced [c][tok]
    {
        int c = tid >> 2, seg = (tid & 3)*32;
        const size_t gbase = basec + (size_t)c*NTOK + seg;
        #pragma unroll
        for (int u = 0; u < 8; ++u){
            float cv[4];
            ld4(OT + c*128 + seg + u*4, cv);
            float4 xv = *(const float4*)(x + gbase + u*4);
            float ga = 1.f + sg[c], be = sbt[c];
            float4 ov;
            ov.x = fmaf(ga, cv[0]+xv.x, be);
            ov.y = fmaf(ga, cv[1]+xv.y, be);
            ov.z = fmaf(ga, cv[2]+xv.z, be);
            ov.w = fmaf(ga, cv[3]+xv.w, be);
            *(float4*)(out + gbase + u*4) = ov;
        }
    }
}

extern "C" void kernel_launch(void* const* d_in, const int* in_sizes, int n_in,
                              void* d_out, int out_size, void* d_ws, size_t ws_size,
                              hipStream_t stream){
    const float* x   = (const float*)d_in[0];
    const float* te  = (const float*)d_in[1];
    const float* qw  = (const float*)d_in[2];
    const float* qb  = (const float*)d_in[3];
    const float* kw  = (const float*)d_in[4];
    const float* kb  = (const float*)d_in[5];
    const float* vw  = (const float*)d_in[6];
    const float* vb  = (const float*)d_in[7];
    const float* ow  = (const float*)d_in[8];
    const float* ob  = (const float*)d_in[9];
    const float* ln1w= (const float*)d_in[10];
    const float* ln1b= (const float*)d_in[11];
    const float* ln2w= (const float*)d_in[12];
    const float* ln2b= (const float*)d_in[13];
    const float* w1  = (const float*)d_in[14];
    const float* b1  = (const float*)d_in[15];
    const float* w2  = (const float*)d_in[16];
    const float* b2  = (const float*)d_in[17];
    const float* cw  = (const float*)d_in[18];
    const float* cb  = (const float*)d_in[19];
    const float* m1w = (const float*)d_in[20];
    const float* m1b = (const float*)d_in[21];
    const float* m2w = (const float*)d_in[22];
    const float* m2b = (const float*)d_in[23];

    char* ws = (char*)d_ws;
    const size_t BUF = (size_t)TOTTOK*64*2;       // 16.78 MB per bf16 buffer
    bf16* Qb_ = (bf16*)(ws);
    bf16* Kb_ = (bf16*)(ws + BUF);
    bf16* Vb_ = (bf16*)(ws + 2*BUF);
    bf16* Hb_ = (bf16*)(ws + 3*BUF);
    float* pool = (float*)(ws + 4*BUF);
    float* gbp  = (float*)(ws + 4*BUF + 32768);

    pool_kernel<<<8192, 128, 0, stream>>>(te, pool);
    film_kernel<<<8, 128, 0, stream>>>(pool, m1w, m1b, m2w, m2b, gbp);
    qkv_kernel<<<TOTTOK/128, 256, 0, stream>>>(x, te, qw, qb, kw, kb, vw, vb, ln1w, ln1b,
                                               Qb_, Kb_, Vb_);
    attn_oproj_kernel<<<TOTTOK/128, 256, 0, stream>>>(Qb_, Kb_, Vb_, ow, ob, Hb_);
    ffn_conv_kernel<<<TOTTOK/128, 256, 0, stream>>>(Hb_, te, x, ln2w, ln2b, w1, b1, w2, b2,
                                                    cw, cb, gbp, (float*)d_out);
}

// Round 4
// 421.585 us; speedup vs baseline: 1.8530x; 1.0049x over previous
//
#include <hip/hip_runtime.h>
#include <hip/hip_bf16.h>

#define NB 8
#define NTOK 16384           // tokens per batch (128*128)
#define TOTTOK (NB*NTOK)     // 131072

typedef __hip_bfloat16 bf16;
typedef __attribute__((ext_vector_type(8))) short bfrag;   // 8 bf16 = 4 VGPR
typedef __attribute__((ext_vector_type(4))) float ffrag;   // 4 fp32 acc

#define MFMA(a,b,c) __builtin_amdgcn_mfma_f32_16x16x32_bf16(a,b,c,0,0,0)

__device__ __forceinline__ float b2f(bf16 v){ return __bfloat162float(v); }
__device__ __forceinline__ bf16 f2b(float v){ return __float2bfloat16(v); }
__device__ __forceinline__ float bfu(unsigned short u){
    union { float f; unsigned v; } x; x.v = ((unsigned)u) << 16; return x.f; }
__device__ __forceinline__ unsigned short ubits(float f){
    union { bf16 b; unsigned short u; } x; x.b = __float2bfloat16(f); return x.u; }
__device__ __forceinline__ bf16 bbits(unsigned short u){
    union { unsigned short u; bf16 b; } x; x.u = u; return x.b; }
// load 4 consecutive bf16 (8B aligned) -> 4 floats
__device__ __forceinline__ void ld4(const bf16* p, float* f){
    uint2 r = *(const uint2*)p;
    f[0]=bfu(r.x & 0xffff); f[1]=bfu(r.x >> 16); f[2]=bfu(r.y & 0xffff); f[3]=bfu(r.y >> 16);
}
// A/B fragment load: matrix row-major [rows][K], p points at [tile_row0][k0].
// lane L: row += L&15, k += (L>>4)*8  (A: row=m; B: row=n, from W^T storage)
__device__ __forceinline__ bfrag ld_frag(const bf16* p, int stride){
    int lane = threadIdx.x & 63;
    return *(const bfrag*)(p + (lane & 15)*stride + (lane >> 4)*8);
}

// ---------------- FiLM pooling: te -> [B,1024] ----------------
__global__ __launch_bounds__(128) void pool_kernel(const float* __restrict__ te,
                                                   float* __restrict__ pool){
    int blk = blockIdx.x;              // b*1024 + c*16 + ph*4 + pw
    int region = blk & 15;
    int c = (blk >> 4) & 63;
    int b = blk >> 10;
    int ph = region >> 2, pw = region & 3;
    const float* base = te + ((size_t)(b*64 + c))*NTOK + (size_t)(ph*32)*128 + pw*32;
    int t = threadIdx.x;
    float s = 0.f;
    #pragma unroll
    for (int j = 0; j < 8; ++j){
        int e = t + j*128;
        int i = e >> 5, w = e & 31;
        s += base[i*128 + w];
    }
    for (int off = 32; off > 0; off >>= 1) s += __shfl_down(s, off, 64);
    __shared__ float tmp[2];
    if ((t & 63) == 0) tmp[t >> 6] = s;
    __syncthreads();
    if (t == 0) pool[blk] = (tmp[0] + tmp[1]) * (1.f/1024.f);
}

// ---------------- FiLM MLP: [B,1024] -> gb[B,128] ----------------
__global__ __launch_bounds__(128) void film_kernel(const float* __restrict__ pool,
        const float* __restrict__ m1w, const float* __restrict__ m1b,
        const float* __restrict__ m2w, const float* __restrict__ m2b,
        float* __restrict__ gb){
    int b = blockIdx.x; int j = threadIdx.x;
    __shared__ float tel[1024];
    __shared__ float hm[128];
    for (int i = j; i < 1024; i += 128) tel[i] = pool[b*1024 + i];
    __syncthreads();
    float s = m1b[j];
    for (int i = 0; i < 1024; ++i) s = fmaf(tel[i], m1w[i*128 + j], s);
    hm[j] = (s > 0.f) ? s : 0.01f*s;
    __syncthreads();
    float g = m2b[j];
    for (int i = 0; i < 128; ++i) g = fmaf(hm[i], m2w[i*128 + j], g);
    gb[b*128 + j] = g;
}

// ---------------- LN1 + QKV (MFMA) -> Q,K,V bf16 [tok][64] ----------------
__global__ __launch_bounds__(256,2) void qkv_kernel(
    const float* __restrict__ x, const float* __restrict__ te,
    const float* __restrict__ qw, const float* __restrict__ qb,
    const float* __restrict__ kw, const float* __restrict__ kb_,
    const float* __restrict__ vw, const float* __restrict__ vb,
    const float* __restrict__ ln1w, const float* __restrict__ ln1b,
    bf16* __restrict__ Qg, bf16* __restrict__ Kg, bf16* __restrict__ Vg)
{
    __shared__ __align__(16) bf16 PN[128*64];     // te tile -> prior_norm ; then Q out
    __shared__ __align__(16) bf16 XT[128*64];     // x tile ; then K out
    __shared__ __align__(16) bf16 WT[3*64*72];    // wq^T,wk^T,wv^T (stride 72) ; then V out
    __shared__ float bias[192];
    __shared__ float lnw[64], lnb[64];
    int tid = threadIdx.x;
    int t0 = blockIdx.x * 128;
    int b = t0 >> 14, n0 = t0 & (NTOK-1);
    const size_t basec = (size_t)b*64*NTOK + n0;
    for (int i = tid; i < 8192; i += 256){
        int c = i >> 7, j = i & 127;
        size_t a = basec + (size_t)c*NTOK + j;
        PN[j*64 + c] = f2b(te[a]);
        XT[j*64 + c] = f2b(x[a]);
    }
    for (int i = tid; i < 4096; i += 256){
        int ii = i >> 6, o = i & 63;
        WT[o*72 + ii]           = f2b(qw[i]);
        WT[4608 + o*72 + ii]    = f2b(kw[i]);
        WT[9216 + o*72 + ii]    = f2b(vw[i]);
    }
    if (tid < 64){ bias[tid]=qb[tid]; bias[64+tid]=kb_[tid]; bias[128+tid]=vb[tid];
                   lnw[tid]=ln1w[tid]; lnb[tid]=ln1b[tid]; }
    __syncthreads();
    {   // LN1 in place on PN: 2 threads per token
        int tok = tid >> 1, half = (tid & 1)*32;
        float vb_[32];
        float s = 0.f, s2 = 0.f;
        #pragma unroll
        for (int u = 0; u < 32; ++u){
            float v = b2f(PN[tok*64 + half + u]);
            vb_[u] = v; s += v; s2 = fmaf(v, v, s2);
        }
        s  += __shfl_xor(s, 1, 64);
        s2 += __shfl_xor(s2, 1, 64);
        float mean = s * (1.f/64.f);
        float var  = s2 * (1.f/64.f) - mean*mean;
        float rstd = rsqrtf(var + 1e-5f);
        #pragma unroll
        for (int u = 0; u < 32; ++u){
            int c = half + u;
            PN[tok*64 + c] = f2b((vb_[u]-mean)*rstd*lnw[c] + lnb[c]);
        }
    }
    __syncthreads();
    int w = tid >> 6, lane = tid & 63;
    ffrag accQ[2][4], accK[2][4], accV[2][4];
    #pragma unroll
    for (int mi=0;mi<2;++mi) for (int nt=0;nt<4;++nt){
        ffrag z = {0.f,0.f,0.f,0.f};
        accQ[mi][nt]=z; accK[mi][nt]=z; accV[mi][nt]=z;
    }
    bfrag aQ[2][2], aX[2][2];
    #pragma unroll
    for (int mi=0;mi<2;++mi) for (int kb2=0;kb2<2;++kb2){
        aQ[mi][kb2] = ld_frag(PN + (w*32 + mi*16)*64 + kb2*32, 64);
        aX[mi][kb2] = ld_frag(XT + (w*32 + mi*16)*64 + kb2*32, 64);
    }
    for (int nt = 0; nt < 4; ++nt){
        #pragma unroll
        for (int kb2 = 0; kb2 < 2; ++kb2){
            bfrag bq2 = ld_frag(WT +        nt*16*72 + kb2*32, 72);
            bfrag bk2 = ld_frag(WT + 4608 + nt*16*72 + kb2*32, 72);
            bfrag bv2 = ld_frag(WT + 9216 + nt*16*72 + kb2*32, 72);
            #pragma unroll
            for (int mi=0;mi<2;++mi){
                accQ[mi][nt] = MFMA(aQ[mi][kb2], bq2, accQ[mi][nt]);
                accK[mi][nt] = MFMA(aX[mi][kb2], bk2, accK[mi][nt]);
                accV[mi][nt] = MFMA(aX[mi][kb2], bv2, accV[mi][nt]);
            }
        }
    }
    __syncthreads();
    int col = lane & 15, rq = (lane >> 4)*4;
    #pragma unroll
    for (int mi=0;mi<2;++mi) for (int nt=0;nt<4;++nt){
        int n = nt*16 + col;
        float bq3 = bias[n], bk3 = bias[64+n], bv3 = bias[128+n];
        #pragma unroll
        for (int r=0;r<4;++r){
            int m = w*32 + mi*16 + rq + r;
            PN[m*64 + n] = f2b(accQ[mi][nt][r] + bq3);
            XT[m*64 + n] = f2b(accK[mi][nt][r] + bk3);
            WT[m*64 + n] = f2b(accV[mi][nt][r] + bv3);
        }
    }
    __syncthreads();
    uint2* gq = (uint2*)(Qg + (size_t)t0*64);
    uint2* gk = (uint2*)(Kg + (size_t)t0*64);
    uint2* gv = (uint2*)(Vg + (size_t)t0*64);
    for (int i = tid; i < 2048; i += 256){
        gq[i] = ((const uint2*)PN)[i];
        gk[i] = ((const uint2*)XT)[i];
        gv[i] = ((const uint2*)WT)[i];
    }
}

// ---------------- MFMA attention + o-proj -> h' bf16 (no residual) ----------------
// Scores: per m-tile (head h, 16 q) build A = Q zero-padded to head h's 4-channel
// slot; one k-step (kb = h>>3) of 16x16x32 vs B=K gives exact per-head scores.
// PV: P stored unnormalized in per-wave LDS scratch, column-permuted (k' = c*8+nt)
// so C-layout regs pack as b128 writes; V staged transposed in same k' order.
// 1/l folds into O epilogue (C-layout rows of O == lane mapping of l).
__global__ __launch_bounds__(256,2) void attn_oproj_kernel(
    const bf16* __restrict__ Qg, const bf16* __restrict__ Kg, const bf16* __restrict__ Vg,
    const float* __restrict__ ow, const float* __restrict__ ob,
    bf16* __restrict__ hout)
{
    __shared__ __align__(16) bf16 QL[128*72];   // 18432 B
    __shared__ __align__(16) bf16 VT[80*136];   // 21760 B  V^T in k'-order, stride 136
    __shared__ __align__(16) bf16 AT[128*64];   // 16384 B  attn output [q][64]
    __shared__ __align__(16) bf16 OWT[64*64];   //  8192 B  o_w^T
    __shared__ __align__(16) bf16 KP[128*64];   // 16384 B  K staging -> P scratch -> h' out
    __shared__ float bo[64];                    // total 81408 B -> 2 blocks/CU
    int tid = threadIdx.x;
    size_t t0 = (size_t)blockIdx.x * 128;
    const uint2* gq = (const uint2*)(Qg + t0*64);
    const uint2* gk = (const uint2*)(Kg + t0*64);
    const uint2* gv = (const uint2*)(Vg + t0*64);
    for (int i = tid; i < 2048; i += 256){
        int m = i >> 4, c4 = (i & 15)*4;
        *(uint2*)(QL + m*72 + c4) = gq[i];
        ((uint2*)KP)[i] = gk[i];
        uint2 rv = gv[i];
        int col = (m & 15)*8 + (m >> 4);        // k' = (k&15)*8 + (k>>4)
        VT[(c4+0)*136 + col] = bbits((unsigned short)(rv.x & 0xffff));
        VT[(c4+1)*136 + col] = bbits((unsigned short)(rv.x >> 16));
        VT[(c4+2)*136 + col] = bbits((unsigned short)(rv.y & 0xffff));
        VT[(c4+3)*136 + col] = bbits((unsigned short)(rv.y >> 16));
    }
    for (int i = tid; i < 4096; i += 256){
        int ii = i >> 6, o = i & 63;
        OWT[o*64 + ii] = f2b(ow[i]);
    }
    if (tid < 64) bo[tid] = ob[tid];
    __syncthreads();
    int lane = tid & 63, w = tid >> 6;
    int g = lane >> 4, c = lane & 15;
    int kb = w >> 1;                            // heads 4w..4w+3 share k-half
    bfrag bq[8];
    #pragma unroll
    for (int nt = 0; nt < 8; ++nt) bq[nt] = ld_frag(KP + nt*16*64 + kb*32, 64);
    __syncthreads();                            // KP becomes P scratch
    bf16* Pw = KP + w*2048;                     // per-wave [16 q][128 k'] bf16
    const ffrag fz = {0.f,0.f,0.f,0.f};
    #pragma unroll
    for (int hh = 0; hh < 4; ++hh){
        int h = w*4 + hh;
        int ag = (h & 7) >> 1;                  // active lane-group for A build
        bfrag bv[4];
        #pragma unroll
        for (int ks = 0; ks < 4; ++ks) bv[ks] = ld_frag(VT + (4*h)*136 + ks*32, 136);
        for (int qt = 0; qt < 8; ++qt){
            int q = qt*16 + c;
            uint2 qv = *(const uint2*)(QL + q*72 + h*4);
            union { bfrag f; uint2 u[2]; } A;
            uint2 z2; z2.x = 0u; z2.y = 0u;
            uint2 sel = (g == ag) ? qv : z2;
            if (hh & 1){ A.u[0] = z2;  A.u[1] = sel; }
            else       { A.u[0] = sel; A.u[1] = z2;  }
            ffrag acc[8];
            #pragma unroll
            for (int nt = 0; nt < 8; ++nt) acc[nt] = MFMA(A.f, bq[nt], fz);
            // p = exp(s/2) = exp2(s * log2e/2); no max-subtraction (tiny scores)
            float l[4] = {0.f,0.f,0.f,0.f};
            #pragma unroll
            for (int nt = 0; nt < 8; ++nt){
                #pragma unroll
                for (int r = 0; r < 4; ++r){
                    float p = exp2f(acc[nt][r] * 0.72134752044448170f);
                    acc[nt][r] = p; l[r] += p;
                }
            }
            #pragma unroll
            for (int r = 0; r < 4; ++r){
                l[r] += __shfl_xor(l[r], 1, 64);
                l[r] += __shfl_xor(l[r], 2, 64);
                l[r] += __shfl_xor(l[r], 4, 64);
                l[r] += __shfl_xor(l[r], 8, 64);
            }
            // pack unnormalized P, XOR-swizzled 16B blocks to spread banks
            #pragma unroll
            for (int r = 0; r < 4; ++r){
                int row = g*4 + r;
                uint4 pk;
                pk.x = (unsigned)ubits(acc[0][r]) | ((unsigned)ubits(acc[1][r]) << 16);
                pk.y = (unsigned)ubits(acc[2][r]) | ((unsigned)ubits(acc[3][r]) << 16);
                pk.z = (unsigned)ubits(acc[4][r]) | ((unsigned)ubits(acc[5][r]) << 16);
                pk.w = (unsigned)ubits(acc[6][r]) | ((unsigned)ubits(acc[7][r]) << 16);
                *(uint4*)(Pw + row*128 + (c ^ (row & 7))*8) = pk;
            }
            ffrag og = fz;
            #pragma unroll
            for (int ks = 0; ks < 4; ++ks){
                bfrag ap = *(const bfrag*)(Pw + c*128 + ((ks*4 + g) ^ (c & 7))*8);
                og = MFMA(ap, bv[ks], og);      // cols >=4 are garbage, ignored
            }
            if (c < 4){
                #pragma unroll
                for (int r = 0; r < 4; ++r){
                    float inv = 1.f / l[r];
                    AT[(qt*16 + g*4 + r)*64 + h*4 + c] = f2b(og[r] * inv);
                }
            }
        }
    }
    __syncthreads();
    // o-proj: D = AT @ OWT^T  (+ bias) -> KP -> global
    ffrag acc2[2][4];
    #pragma unroll
    for (int mi=0;mi<2;++mi) for (int nt=0;nt<4;++nt) acc2[mi][nt] = fz;
    bfrag af2[2][2];
    #pragma unroll
    for (int mi=0;mi<2;++mi){
        #pragma unroll
        for (int kb2=0;kb2<2;++kb2)
            af2[mi][kb2] = ld_frag(AT + (w*32 + mi*16)*64 + kb2*32, 64);
    }
    #pragma unroll
    for (int nt=0;nt<4;++nt){
        #pragma unroll
        for (int kb2=0;kb2<2;++kb2){
            bfrag bf_ = ld_frag(OWT + nt*16*64 + kb2*32, 64);
            #pragma unroll
            for (int mi=0;mi<2;++mi) acc2[mi][nt] = MFMA(af2[mi][kb2], bf_, acc2[mi][nt]);
        }
    }
    int rq = (lane >> 4)*4;
    #pragma unroll
    for (int mi=0;mi<2;++mi) for (int nt=0;nt<4;++nt){
        int n = nt*16 + c;
        #pragma unroll
        for (int r=0;r<4;++r){
            int m = w*32 + mi*16 + rq + r;
            KP[m*64 + n] = f2b(acc2[mi][nt][r] + bo[n]);
        }
    }
    __syncthreads();
    uint2* gh = (uint2*)(hout + t0*64);
    for (int i = tid; i < 2048; i += 256) gh[i] = ((const uint2*)KP)[i];
}

// ---------------- h'+te residual, LN2, fc1+GELU, fc2+residual, conv, FiLM -> out ----------------
__global__ __launch_bounds__(256,2) void ffn_conv_kernel(
    const bf16* __restrict__ hg, const float* __restrict__ te, const float* __restrict__ x,
    const float* __restrict__ ln2w, const float* __restrict__ ln2b,
    const float* __restrict__ w1, const float* __restrict__ b1,
    const float* __restrict__ w2, const float* __restrict__ b2,
    const float* __restrict__ cw, const float* __restrict__ cb,
    const float* __restrict__ gb, float* __restrict__ out)
{
    __shared__ float sb1[256];
    __shared__ float sb2[64], slw[64], slb[64], scb[64], sg[64], sbt[64];
    __shared__ __align__(16) bf16 W2T[64*264];  // w2^T [o][k], stride 264
    __shared__ __align__(16) bf16 H[128*64];    // h ; later OT [c][tok] (conv out)
    __shared__ __align__(16) bf16 HN[128*64];   // te stage -> h_norm -> h2
    __shared__ __align__(16) bf16 WP[6400];     // W1S (2304) + P (4096) ; later convW
    bf16* W1S = WP;
    bf16* P   = WP + 2304;
    bf16* CWs = WP;
    int tid = threadIdx.x;
    int t0 = blockIdx.x * 128;
    int b = t0 >> 14, n0 = t0 & (NTOK-1);
    const size_t basec = (size_t)b*64*NTOK + n0;
    {
        const uint2* ghp = (const uint2*)(hg + (size_t)t0*64);
        for (int i = tid; i < 2048; i += 256) ((uint2*)H)[i] = ghp[i];
    }
    for (int i = tid; i < 8192; i += 256){
        int c = i >> 7, j = i & 127;
        HN[j*64 + c] = f2b(te[basec + (size_t)c*NTOK + j]);
    }
    for (int i = tid; i < 16384; i += 256){
        int k = i >> 6, o = i & 63;
        W2T[o*264 + k] = f2b(w2[i]);
    }
    if (tid < 64){ sb2[tid]=b2[tid]; slw[tid]=ln2w[tid]; slb[tid]=ln2b[tid];
                   scb[tid]=cb[tid]; sg[tid]=gb[b*128+tid]; sbt[tid]=gb[b*128+64+tid]; }
    sb1[tid] = b1[tid];
    __syncthreads();
    for (int i = tid; i < 8192; i += 256) H[i] = f2b(b2f(H[i]) + b2f(HN[i]));
    __syncthreads();
    {
        int tok = tid >> 1, half = (tid & 1)*32;
        float vb_[32];
        float s = 0.f, s2 = 0.f;
        #pragma unroll
        for (int u = 0; u < 32; ++u){
            float v = b2f(H[tok*64 + half + u]);
            vb_[u] = v; s += v; s2 = fmaf(v, v, s2);
        }
        s  += __shfl_xor(s, 1, 64);
        s2 += __shfl_xor(s2, 1, 64);
        float mean = s * (1.f/64.f);
        float var  = s2 * (1.f/64.f) - mean*mean;
        float rstd = rsqrtf(var + 1e-5f);
        #pragma unroll
        for (int u = 0; u < 32; ++u){
            int c = half + u;
            HN[tok*64 + c] = f2b((vb_[u]-mean)*rstd*slw[c] + slb[c]);
        }
    }
    __syncthreads();
    int w = tid >> 6, lane = tid & 63;
    int col = lane & 15, rq = (lane >> 4)*4;
    bfrag af[2][2];
    #pragma unroll
    for (int mi=0;mi<2;++mi) for (int kb2=0;kb2<2;++kb2)
        af[mi][kb2] = ld_frag(HN + (w*32 + mi*16)*64 + kb2*32, 64);
    ffrag acc2[2][4];
    #pragma unroll
    for (int mi=0;mi<2;++mi) for (int nt=0;nt<4;++nt){ ffrag z={0.f,0.f,0.f,0.f}; acc2[mi][nt]=z; }
    for (int g = 0; g < 8; ++g){
        __syncthreads();
        for (int i = tid; i < 2048; i += 256){
            int ol = i & 31, ii = i >> 5;
            W1S[ol*72 + ii] = f2b(w1[ii*256 + g*32 + ol]);
        }
        __syncthreads();
        ffrag accg[2][2];
        #pragma unroll
        for (int mi=0;mi<2;++mi) for (int ntl=0;ntl<2;++ntl){ ffrag z={0.f,0.f,0.f,0.f}; accg[mi][ntl]=z; }
        #pragma unroll
        for (int ntl=0;ntl<2;++ntl){
            #pragma unroll
            for (int kb2=0;kb2<2;++kb2){
                bfrag bf_ = ld_frag(W1S + ntl*16*72 + kb2*32, 72);
                #pragma unroll
                for (int mi=0;mi<2;++mi) accg[mi][ntl] = MFMA(af[mi][kb2], bf_, accg[mi][ntl]);
            }
        }
        #pragma unroll
        for (int mi=0;mi<2;++mi) for (int ntl=0;ntl<2;++ntl){
            int n = ntl*16 + col;
            float bb = sb1[g*32 + n];
            #pragma unroll
            for (int r=0;r<4;++r){
                int m = w*32 + mi*16 + rq + r;
                float xv = accg[mi][ntl][r] + bb;
                P[m*32 + n] = f2b(0.5f*xv*(1.f + erff(xv*0.70710678118654752f)));
            }
        }
        #pragma unroll
        for (int mi=0;mi<2;++mi){
            bfrag ap = ld_frag(P + (w*32 + mi*16)*32, 32);
            #pragma unroll
            for (int nt=0;nt<4;++nt){
                bfrag bf2 = ld_frag(W2T + nt*16*264 + g*32, 264);
                acc2[mi][nt] = MFMA(ap, bf2, acc2[mi][nt]);
            }
        }
    }
    __syncthreads();
    #pragma unroll
    for (int mi=0;mi<2;++mi) for (int nt=0;nt<4;++nt){
        int n = nt*16 + col;
        #pragma unroll
        for (int r=0;r<4;++r){
            int m = w*32 + mi*16 + rq + r;
            HN[m*64 + n] = f2b(acc2[mi][nt][r] + sb2[n] + b2f(H[m*64 + n]));
        }
    }
    for (int i = tid; i < 4096; i += 256){
        int c = i >> 6, ii = i & 63;
        CWs[c*72 + ii] = f2b(cw[i]);
    }
    __syncthreads();
    bf16* OT = H;  // [64][128]
    {
        bfrag ac[2];
        #pragma unroll
        for (int kb2=0;kb2<2;++kb2) ac[kb2] = ld_frag(CWs + w*16*72 + kb2*32, 72);
        for (int nt = 0; nt < 8; ++nt){
            ffrag accc = {0.f,0.f,0.f,0.f};
            #pragma unroll
            for (int kb2=0;kb2<2;++kb2){
                bfrag bh = ld_frag(HN + nt*16*64 + kb2*32, 64);
                accc = MFMA(ac[kb2], bh, accc);
            }
            int tok = nt*16 + col;
            #pragma unroll
            for (int r=0;r<4;++r){
                int c = w*16 + rq + r;
                OT[c*128 + tok] = f2b(accc[r] + scb[c]);
            }
        }
    }
    __syncthreads();
    {
        int c = tid >> 2, seg = (tid & 3)*32;
        const size_t gbase = basec + (size_t)c*NTOK + seg;
        #pragma unroll
        for (int u = 0; u < 8; ++u){
            float cv[4];
            ld4(OT + c*128 + seg + u*4, cv);
            float4 xv = *(const float4*)(x + gbase + u*4);
            float ga = 1.f + sg[c], be = sbt[c];
            float4 ov;
            ov.x = fmaf(ga, cv[0]+xv.x, be);
            ov.y = fmaf(ga, cv[1]+xv.y, be);
            ov.z = fmaf(ga, cv[2]+xv.z, be);
            ov.w = fmaf(ga, cv[3]+xv.w, be);
            *(float4*)(out + gbase + u*4) = ov;
        }
    }
}

extern "C" void kernel_launch(void* const* d_in, const int* in_sizes, int n_in,
                              void* d_out, int out_size, void* d_ws, size_t ws_size,
                              hipStream_t stream){
    const float* x   = (const float*)d_in[0];
    const float* te  = (const float*)d_in[1];
    const float* qw  = (const float*)d_in[2];
    const float* qb  = (const float*)d_in[3];
    const float* kw  = (const float*)d_in[4];
    const float* kb  = (const float*)d_in[5];
    const float* vw  = (const float*)d_in[6];
    const float* vb  = (const float*)d_in[7];
    const float* ow  = (const float*)d_in[8];
    const float* ob  = (const float*)d_in[9];
    const float* ln1w= (const float*)d_in[10];
    const float* ln1b= (const float*)d_in[11];
    const float* ln2w= (const float*)d_in[12];
    const float* ln2b= (const float*)d_in[13];
    const float* w1  = (const float*)d_in[14];
    const float* b1  = (const float*)d_in[15];
    const float* w2  = (const float*)d_in[16];
    const float* b2  = (const float*)d_in[17];
    const float* cw  = (const float*)d_in[18];
    const float* cb  = (const float*)d_in[19];
    const float* m1w = (const float*)d_in[20];
    const float* m1b = (const float*)d_in[21];
    const float* m2w = (const float*)d_in[22];
    const float* m2b = (const float*)d_in[23];

    char* ws = (char*)d_ws;
    const size_t BUF = (size_t)TOTTOK*64*2;       // 16.78 MB per bf16 buffer
    bf16* Qb_ = (bf16*)(ws);
    bf16* Kb_ = (bf16*)(ws + BUF);
    bf16* Vb_ = (bf16*)(ws + 2*BUF);
    bf16* Hb_ = (bf16*)(ws + 3*BUF);
    float* pool = (float*)(ws + 4*BUF);
    float* gbp  = (float*)(ws + 4*BUF + 32768);

    pool_kernel<<<8192, 128, 0, stream>>>(te, pool);
    film_kernel<<<8, 128, 0, stream>>>(pool, m1w, m1b, m2w, m2b, gbp);
    qkv_kernel<<<TOTTOK/128, 256, 0, stream>>>(x, te, qw, qb, kw, kb, vw, vb, ln1w, ln1b,
                                               Qb_, Kb_, Vb_);
    attn_oproj_kernel<<<TOTTOK/128, 256, 0, stream>>>(Qb_, Kb_, Vb_, ow, ob, Hb_);
    ffn_conv_kernel<<<TOTTOK/128, 256, 0, stream>>>(Hb_, te, x, ln2w, ln2b, w1, b1, w2, b2,
                                                    cw, cb, gbp, (float*)d_out);
}

// Round 5
// 399.240 us; speedup vs baseline: 1.9567x; 1.0560x over previous
//
#include <hip/hip_runtime.h>
#include <hip/hip_bf16.h>

#define NB 8
#define NTOK 16384           // tokens per batch (128*128)
#define TOTTOK (NB*NTOK)     // 131072

typedef __hip_bfloat16 bf16;
typedef __attribute__((ext_vector_type(8))) short bfrag;   // 8 bf16 = 4 VGPR
typedef __attribute__((ext_vector_type(4))) float ffrag;   // 4 fp32 acc

#define MFMA(a,b,c) __builtin_amdgcn_mfma_f32_16x16x32_bf16(a,b,c,0,0,0)

__device__ __forceinline__ float b2f(bf16 v){ return __bfloat162float(v); }
__device__ __forceinline__ bf16 f2b(float v){ return __float2bfloat16(v); }
__device__ __forceinline__ float bfu(unsigned short u){
    union { float f; unsigned v; } x; x.v = ((unsigned)u) << 16; return x.f; }
__device__ __forceinline__ unsigned short ubits(float f){
    union { bf16 b; unsigned short u; } x; x.b = __float2bfloat16(f); return x.u; }
__device__ __forceinline__ unsigned short bu(bf16 b){
    union { bf16 b; unsigned short u; } x; x.b = b; return x.u; }
__device__ __forceinline__ void ld4(const bf16* p, float* f){
    uint2 r = *(const uint2*)p;
    f[0]=bfu(r.x & 0xffff); f[1]=bfu(r.x >> 16); f[2]=bfu(r.y & 0xffff); f[3]=bfu(r.y >> 16);
}
// A/B fragment: matrix row-major [rows][K]; lane L: row += L&15, k += (L>>4)*8.
// stride*2 bytes MUST be a multiple of 16 (b128 alignment).
__device__ __forceinline__ bfrag ld_frag(const bf16* p, int stride){
    int lane = threadIdx.x & 63;
    return *(const bfrag*)(p + (lane & 15)*stride + (lane >> 4)*8);
}

// ============ transpose prepass: fp32 [B,C,N] -> bf16 [B,N,C]; + FiLM pool partials ============
__global__ __launch_bounds__(256) void transpose_kernel(
    const float* __restrict__ x, const float* __restrict__ te,
    bf16* __restrict__ xT, bf16* __restrict__ teT, float* __restrict__ pool)
{
    __shared__ bf16 T[64*66];
    int blk = blockIdx.x;            // b*256 + tile
    int tile = blk & 255, b = blk >> 8;
    int t0 = tile * 64;              // token base within batch
    const size_t sbase = (size_t)b*64*NTOK + t0;
    const size_t obase = ((size_t)b*NTOK + t0)*64;
    int tid = threadIdx.x;
    // ---- x ----
    #pragma unroll
    for (int p = 0; p < 4; ++p){
        int c = p*16 + (tid >> 4), j4 = (tid & 15)*4;
        float4 v = *(const float4*)(x + sbase + (size_t)c*NTOK + j4);
        bf16* tp = T + c*66 + j4;
        tp[0]=f2b(v.x); tp[1]=f2b(v.y); tp[2]=f2b(v.z); tp[3]=f2b(v.w);
    }
    __syncthreads();
    #pragma unroll
    for (int p = 0; p < 4; ++p){
        int j = p*16 + (tid >> 4), c4 = (tid & 15)*4;
        uint2 o;
        o.x = (unsigned)bu(T[(c4+0)*66 + j]) | ((unsigned)bu(T[(c4+1)*66 + j]) << 16);
        o.y = (unsigned)bu(T[(c4+2)*66 + j]) | ((unsigned)bu(T[(c4+3)*66 + j]) << 16);
        *(uint2*)(xT + obase + (size_t)j*64 + c4) = o;
    }
    __syncthreads();
    // ---- te ----
    #pragma unroll
    for (int p = 0; p < 4; ++p){
        int c = p*16 + (tid >> 4), j4 = (tid & 15)*4;
        float4 v = *(const float4*)(te + sbase + (size_t)c*NTOK + j4);
        bf16* tp = T + c*66 + j4;
        tp[0]=f2b(v.x); tp[1]=f2b(v.y); tp[2]=f2b(v.z); tp[3]=f2b(v.w);
    }
    __syncthreads();
    #pragma unroll
    for (int p = 0; p < 4; ++p){
        int j = p*16 + (tid >> 4), c4 = (tid & 15)*4;
        uint2 o;
        o.x = (unsigned)bu(T[(c4+0)*66 + j]) | ((unsigned)bu(T[(c4+1)*66 + j]) << 16);
        o.y = (unsigned)bu(T[(c4+2)*66 + j]) | ((unsigned)bu(T[(c4+3)*66 + j]) << 16);
        *(uint2*)(teT + obase + (size_t)j*64 + c4) = o;
    }
    // ---- FiLM pool partials (sum te over 32-token halves per channel) ----
    if (tid < 128){
        int c = tid >> 1, hf = tid & 1;
        float s = 0.f;
        #pragma unroll
        for (int u = 0; u < 32; ++u) s += b2f(T[c*66 + hf*32 + u]);
        int h = t0 >> 7;             // spatial row (W=128)
        int w0 = t0 & 127;           // 0 or 64
        int region = (h >> 5)*4 + ((w0 + hf*32) >> 5);
        atomicAdd(pool + b*1024 + c*16 + region, s);
    }
}

// ============ FiLM MLP: pool[B,1024] (unnormalized sums) -> gb[B,128] ============
__global__ __launch_bounds__(128) void film_kernel(const float* __restrict__ pool,
        const float* __restrict__ m1w, const float* __restrict__ m1b,
        const float* __restrict__ m2w, const float* __restrict__ m2b,
        float* __restrict__ gb){
    int b = blockIdx.x; int j = threadIdx.x;
    __shared__ float tel[1024];
    __shared__ float hm[128];
    for (int i = j; i < 1024; i += 128) tel[i] = pool[b*1024 + i] * (1.f/1024.f);
    __syncthreads();
    float s = m1b[j];
    for (int i = 0; i < 1024; ++i) s = fmaf(tel[i], m1w[i*128 + j], s);
    hm[j] = (s > 0.f) ? s : 0.01f*s;
    __syncthreads();
    float g = m2b[j];
    for (int i = 0; i < 128; ++i) g = fmaf(hm[i], m2w[i*128 + j], g);
    gb[b*128 + j] = g;
}

// ============ MEGA kernel: full TIAM block per 128-token chunk ============
// LDS map (manual overlays, 81920 B total -> 2 blocks/CU):
//  [    0,16384) TE2 [128][64] raw te  -> H [128][64]          -> OT [64][128]
//  [16384,34816) XTt [128][72] x tile  -> K  -> Pw(4x[16][128]) -> h'[128][72] -> HN [128][72]
//  [34816,53248) PN  [128][72] LN1-out -> Q/O [128][72]         -> W1S [32][72] + P [128][32]  -> CWs [64][72]
//  [53248,80896) WT 3x[64][72]         -> VT [80][136] (+ harmless overflow reads) -> OWT [64][72]
//  [47616,80384) W2T [64][256] k-xor-swizzled (phase6 only; over dead PN-tail+WT)
//  [80896,81920) CON consts (restaged per phase)
#define OFF_TE2 0
#define OFF_XT  16384
#define OFF_PN  34816
#define OFF_WT  53248
#define OFF_W2T 47616
#define OFF_CON 80896
#define SCALE_Q 0.72134752044448170f   // 0.5 * log2(e): fold softmax scale + exp2 conv into Q

__global__ __launch_bounds__(256,2) void mega_kernel(
    const bf16* __restrict__ xT, const bf16* __restrict__ teT, const float* __restrict__ x,
    const float* __restrict__ qw, const float* __restrict__ kw, const float* __restrict__ vw,
    const float* __restrict__ qb, const float* __restrict__ kb_, const float* __restrict__ vb,
    const float* __restrict__ ln1w, const float* __restrict__ ln1b,
    const float* __restrict__ ow, const float* __restrict__ ob,
    const float* __restrict__ ln2w, const float* __restrict__ ln2b,
    const float* __restrict__ w1, const float* __restrict__ b1,
    const float* __restrict__ w2, const float* __restrict__ b2,
    const float* __restrict__ cw, const float* __restrict__ cb,
    const float* __restrict__ gb, float* __restrict__ out)
{
    __shared__ __align__(16) char sm[81920];
    bf16* TE2 = (bf16*)(sm + OFF_TE2);
    bf16* XT  = (bf16*)(sm + OFF_XT);
    bf16* PN  = (bf16*)(sm + OFF_PN);
    bf16* WT  = (bf16*)(sm + OFF_WT);
    bf16* VT  = (bf16*)(sm + OFF_WT);
    bf16* OWT = (bf16*)(sm + OFF_WT);
    bf16* W1S = (bf16*)(sm + OFF_PN);
    bf16* P   = (bf16*)(sm + OFF_PN + 4608);
    bf16* CWs = (bf16*)(sm + OFF_PN);
    bf16* W2T = (bf16*)(sm + OFF_W2T);
    bf16* CON = (bf16*)(sm + OFF_CON);
    bf16* OT  = (bf16*)(sm + OFF_TE2);

    int tid = threadIdx.x;
    int w = tid >> 6, lane = tid & 63;
    int g = lane >> 4, c = lane & 15;
    int t0g = blockIdx.x * 128;               // global token base
    int b = t0g >> 14, n0 = t0g & (NTOK-1);
    const ffrag fz = {0.f,0.f,0.f,0.f};

    // ---------- phase 0: stage tiles + qkv weights + ln1 consts ----------
    {
        const uint4* gx = (const uint4*)(xT + (size_t)t0g*64);
        const uint4* gt = (const uint4*)(teT + (size_t)t0g*64);
        #pragma unroll
        for (int p = 0; p < 4; ++p){
            int i = tid + p*256;              // 1024 x 16B
            int tok = i >> 3, seg = i & 7;
            *(uint4*)(XT + tok*72 + seg*8) = gx[i];
            ((uint4*)TE2)[i] = gt[i];
        }
        for (int i = tid; i < 4096; i += 256){
            int ii = i >> 6, o = i & 63;
            WT[o*72 + ii]        = f2b(qw[i]);
            WT[4608 + o*72 + ii] = f2b(kw[i]);
            WT[9216 + o*72 + ii] = f2b(vw[i]);
        }
        if (tid < 128) CON[tid] = f2b(tid < 64 ? ln1w[tid] : ln1b[tid-64]);
    }
    __syncthreads();
    // ---------- phase 1: LN1 (TE2 -> PN), bank-rotated ----------
    {
        int tok = tid >> 1, hf = tid & 1;
        float vals[32];
        float s = 0.f, s2 = 0.f;
        #pragma unroll
        for (int u = 0; u < 32; ++u){
            int cc = hf*32 + ((u + tok) & 31);
            float v = b2f(TE2[tok*64 + cc]);
            vals[u] = v; s += v; s2 = fmaf(v, v, s2);
        }
        s  += __shfl_xor(s, 1, 64);
        s2 += __shfl_xor(s2, 1, 64);
        float mean = s * (1.f/64.f);
        float var  = s2 * (1.f/64.f) - mean*mean;
        float rstd = rsqrtf(var + 1e-5f);
        #pragma unroll
        for (int u = 0; u < 32; ++u){
            int cc = hf*32 + ((u + tok) & 31);
            PN[tok*72 + cc] = f2b((vals[u]-mean)*rstd*b2f(CON[cc]) + b2f(CON[64+cc]));
        }
    }
    __syncthreads();
    // ---------- phase 2: QKV MFMA ----------
    {
        // stage qkv biases (ln1 consts dead)
        if (tid < 192){
            int which = tid >> 6, o = tid & 63;
            float v = (which==0) ? qb[o] : (which==1) ? kb_[o] : vb[o];
            CON[tid] = f2b(v);
        }
        ffrag accQ[2][4], accK[2][4], accV[2][4];
        #pragma unroll
        for (int mi=0;mi<2;++mi) for (int nt=0;nt<4;++nt){ accQ[mi][nt]=fz; accK[mi][nt]=fz; accV[mi][nt]=fz; }
        bfrag aQ[2][2], aX[2][2];
        #pragma unroll
        for (int mi=0;mi<2;++mi) for (int k2=0;k2<2;++k2){
            aQ[mi][k2] = ld_frag(PN + (w*32 + mi*16)*72 + k2*32, 72);
            aX[mi][k2] = ld_frag(XT + (w*32 + mi*16)*72 + k2*32, 72);
        }
        for (int nt = 0; nt < 4; ++nt){
            #pragma unroll
            for (int k2 = 0; k2 < 2; ++k2){
                bfrag bq2 = ld_frag(WT +        nt*16*72 + k2*32, 72);
                bfrag bk2 = ld_frag(WT + 4608 + nt*16*72 + k2*32, 72);
                bfrag bv2 = ld_frag(WT + 9216 + nt*16*72 + k2*32, 72);
                #pragma unroll
                for (int mi=0;mi<2;++mi){
                    accQ[mi][nt] = MFMA(aQ[mi][k2], bq2, accQ[mi][nt]);
                    accK[mi][nt] = MFMA(aX[mi][k2], bk2, accK[mi][nt]);
                    accV[mi][nt] = MFMA(aX[mi][k2], bv2, accV[mi][nt]);
                }
            }
        }
        __syncthreads();   // all PN/XT/WT reads done; regions become Q / K / VT
        int rq = g*4;
        #pragma unroll
        for (int mi=0;mi<2;++mi) for (int nt=0;nt<4;++nt){
            int n = nt*16 + c;
            float bq3 = b2f(CON[n]), bk3 = b2f(CON[64+n]), bv3 = b2f(CON[128+n]);
            #pragma unroll
            for (int r=0;r<4;++r){
                int m = w*32 + mi*16 + rq + r;
                PN[m*72 + n] = f2b((accQ[mi][nt][r] + bq3) * SCALE_Q);   // Q (pre-scaled)
                XT[m*72 + n] = f2b(accK[mi][nt][r] + bk3);               // K
                // V -> VT transposed: channel n -> row 5*(n>>2)+(n&3); key m -> col k'
                int kp = (m & 15)*8 + (m >> 4);
                VT[(5*(n>>2) + (n&3))*136 + kp] = f2b(accV[mi][nt][r] + bv3);
            }
        }
        // ones rows (row 5h+4) for the l-trick
        const bf16 one = f2b(1.0f);
        for (int i = tid; i < 2048; i += 256)
            VT[(5*(i>>7) + 4)*136 + (i & 127)] = one;
    }
    __syncthreads();
    // ---------- phase 3: attention (block-diag, 16 heads, hd=4) ----------
    {
        int kb = w >> 1;                       // k-half for this wave's heads
        bfrag bq[8];
        #pragma unroll
        for (int nt = 0; nt < 8; ++nt) bq[nt] = ld_frag(XT + nt*16*72 + kb*32, 72);
        __syncthreads();                       // K region becomes P scratch
        bf16* Pw = XT + w*2048;                // per-wave [16][128]
        #pragma unroll 1
        for (int hh = 0; hh < 4; ++hh){
            int h = w*4 + hh;
            int ag = (h & 7) >> 1;             // active quad for A build
            bfrag bv4[4];
            #pragma unroll
            for (int ks = 0; ks < 4; ++ks) bv4[ks] = ld_frag(VT + (5*h)*136 + ks*32, 136);
            #pragma unroll 2
            for (int qt = 0; qt < 8; ++qt){
                int q = qt*16 + c;
                uint2 qv = *(const uint2*)(PN + q*72 + h*4);
                union { bfrag f; uint2 u[2]; } A;
                uint2 z2; z2.x = 0u; z2.y = 0u;
                uint2 sel = (g == ag) ? qv : z2;
                if (hh & 1){ A.u[0] = z2;  A.u[1] = sel; }
                else       { A.u[0] = sel; A.u[1] = z2;  }
                ffrag acc[8];
                #pragma unroll
                for (int nt = 0; nt < 8; ++nt) acc[nt] = MFMA(A.f, bq[nt], fz);
                #pragma unroll
                for (int nt = 0; nt < 8; ++nt){
                    #pragma unroll
                    for (int r = 0; r < 4; ++r) acc[nt][r] = exp2f(acc[nt][r]);
                }
                // pack unnormalized P: row m=4g+r, col k' = c*8 + nt
                #pragma unroll
                for (int r = 0; r < 4; ++r){
                    uint4 pk;
                    pk.x = (unsigned)ubits(acc[0][r]) | ((unsigned)ubits(acc[1][r]) << 16);
                    pk.y = (unsigned)ubits(acc[2][r]) | ((unsigned)ubits(acc[3][r]) << 16);
                    pk.z = (unsigned)ubits(acc[4][r]) | ((unsigned)ubits(acc[5][r]) << 16);
                    pk.w = (unsigned)ubits(acc[6][r]) | ((unsigned)ubits(acc[7][r]) << 16);
                    *(uint4*)(Pw + (4*g + r)*128 + c*8) = pk;
                }
                ffrag og = fz;
                #pragma unroll
                for (int ks = 0; ks < 4; ++ks){
                    bfrag ap = *(const bfrag*)(Pw + c*128 + (ks*4 + g)*8);
                    og = MFMA(ap, bv4[ks], og);    // cols: 0..3 = O, 4 = l (ones row)
                }
                // broadcast l from lanes c==4, normalize, write O over Q (own wave's cols)
                #pragma unroll
                for (int r = 0; r < 4; ++r){
                    float lr = __shfl(og[r], (lane & 48) | 4, 64);
                    if (c < 4)
                        PN[(qt*16 + 4*g + r)*72 + h*4 + c] = f2b(og[r] / lr);
                }
            }
        }
    }
    __syncthreads();
    // ---------- phase 3.5: o-proj (O @ ow^T + ob) -> h' ----------
    {
        for (int i = tid; i < 4096; i += 256){
            int ii = i >> 6, o = i & 63;
            OWT[o*72 + ii] = f2b(ow[i]);
        }
        if (tid < 64) CON[tid] = f2b(ob[tid]);
        if (tid >= 64 && tid < 192) CON[tid] = f2b(tid < 128 ? ln2w[tid-64] : ln2b[tid-128]);
        __syncthreads();
        ffrag acc2[2][4];
        #pragma unroll
        for (int mi=0;mi<2;++mi) for (int nt=0;nt<4;++nt) acc2[mi][nt] = fz;
        bfrag af2[2][2];
        #pragma unroll
        for (int mi=0;mi<2;++mi) for (int k2=0;k2<2;++k2)
            af2[mi][k2] = ld_frag(PN + (w*32 + mi*16)*72 + k2*32, 72);
        #pragma unroll
        for (int nt=0;nt<4;++nt){
            #pragma unroll
            for (int k2=0;k2<2;++k2){
                bfrag bf_ = ld_frag(OWT + nt*16*72 + k2*32, 72);
                #pragma unroll
                for (int mi=0;mi<2;++mi) acc2[mi][nt] = MFMA(af2[mi][k2], bf_, acc2[mi][nt]);
            }
        }
        __syncthreads();                       // Pw dead; XT region becomes h'
        int rq = g*4;
        #pragma unroll
        for (int mi=0;mi<2;++mi) for (int nt=0;nt<4;++nt){
            int n = nt*16 + c;
            float bo = b2f(CON[n]);
            #pragma unroll
            for (int r=0;r<4;++r){
                int m = w*32 + mi*16 + rq + r;
                XT[m*72 + n] = f2b(acc2[mi][nt][r] + bo);
            }
        }
    }
    __syncthreads();
    // ---------- phase 4: h = h' + te (into TE2 region, stride 64) ----------
    for (int i = tid; i < 8192; i += 256){
        int tok = i >> 6, cc = i & 63;
        TE2[i] = f2b(b2f(TE2[i]) + b2f(XT[tok*72 + cc]));
    }
    __syncthreads();
    // ---------- phase 5: LN2 (TE2 -> HN in XT region) ----------
    {
        int tok = tid >> 1, hf = tid & 1;
        float vals[32];
        float s = 0.f, s2 = 0.f;
        #pragma unroll
        for (int u = 0; u < 32; ++u){
            int cc = hf*32 + ((u + tok) & 31);
            float v = b2f(TE2[tok*64 + cc]);
            vals[u] = v; s += v; s2 = fmaf(v, v, s2);
        }
        s  += __shfl_xor(s, 1, 64);
        s2 += __shfl_xor(s2, 1, 64);
        float mean = s * (1.f/64.f);
        float var  = s2 * (1.f/64.f) - mean*mean;
        float rstd = rsqrtf(var + 1e-5f);
        #pragma unroll
        for (int u = 0; u < 32; ++u){
            int cc = hf*32 + ((u + tok) & 31);
            XT[tok*72 + cc] = f2b((vals[u]-mean)*rstd*b2f(CON[64+cc]) + b2f(CON[128+cc]));
        }
    }
    __syncthreads();
    // ---------- phase 6: FFN (fc1+GELU+fc2, K-grouped) + residual ----------
    {
        // stage W2T (k-chunk xor swizzle) + consts (b1 @CON, b2 @CON+256, cb @CON+320 as bf16 idx)
        for (int i = tid; i < 16384; i += 256){
            int k = i >> 6, o = i & 63;
            W2T[o*256 + (((k>>3) ^ (o&7)) << 3) + (k & 7)] = f2b(w2[i]);
        }
        CON[tid] = f2b(b1[tid]);
        if (tid < 64){ CON[256+tid] = f2b(b2[tid]); CON[320+tid] = f2b(cb[tid]); }
        bfrag af[2][2];
        #pragma unroll
        for (int mi=0;mi<2;++mi) for (int k2=0;k2<2;++k2)
            af[mi][k2] = ld_frag(XT + (w*32 + mi*16)*72 + k2*32, 72);
        ffrag acc2[2][4];
        #pragma unroll
        for (int mi=0;mi<2;++mi) for (int nt=0;nt<4;++nt) acc2[mi][nt] = fz;
        int rq = g*4;
        for (int gg = 0; gg < 8; ++gg){
            __syncthreads();
            for (int i = tid; i < 2048; i += 256){
                int ol = i & 31, ii = i >> 5;
                W1S[ol*72 + ii] = f2b(w1[ii*256 + gg*32 + ol]);
            }
            __syncthreads();
            ffrag accg[2][2];
            #pragma unroll
            for (int mi=0;mi<2;++mi) for (int ntl=0;ntl<2;++ntl) accg[mi][ntl] = fz;
            #pragma unroll
            for (int ntl=0;ntl<2;++ntl){
                #pragma unroll
                for (int k2=0;k2<2;++k2){
                    bfrag bf_ = ld_frag(W1S + ntl*16*72 + k2*32, 72);
                    #pragma unroll
                    for (int mi=0;mi<2;++mi) accg[mi][ntl] = MFMA(af[mi][k2], bf_, accg[mi][ntl]);
                }
            }
            // GELU -> P (own rows; no barrier needed before own-row frag reads)
            #pragma unroll
            for (int mi=0;mi<2;++mi) for (int ntl=0;ntl<2;++ntl){
                int n = ntl*16 + c;
                float bb = b2f(CON[gg*32 + n]);
                #pragma unroll
                for (int r=0;r<4;++r){
                    int m = w*32 + mi*16 + rq + r;
                    float xv = accg[mi][ntl][r] + bb;
                    P[m*32 + n] = f2b(0.5f*xv*(1.f + erff(xv*0.70710678118654752f)));
                }
            }
            // fc2 partial (K-chunk gg), swizzled W2T frag
            #pragma unroll
            for (int mi=0;mi<2;++mi){
                bfrag ap = ld_frag(P + (w*32 + mi*16)*32, 32);
                #pragma unroll
                for (int nt=0;nt<4;++nt){
                    int n = nt*16 + c;
                    int chunk = gg*4 + g;
                    bfrag bf2 = *(const bfrag*)(W2T + n*256 + ((chunk ^ (n&7)) << 3));
                    acc2[mi][nt] = MFMA(ap, bf2, acc2[mi][nt]);
                }
            }
        }
        // h2 = fc2 + b2 + h  -> HN (over LN2 output; af already in regs for all waves)
        #pragma unroll
        for (int mi=0;mi<2;++mi) for (int nt=0;nt<4;++nt){
            int n = nt*16 + c;
            float bb = b2f(CON[256+n]);
            #pragma unroll
            for (int r=0;r<4;++r){
                int m = w*32 + mi*16 + rq + r;
                XT[m*72 + n] = f2b(acc2[mi][nt][r] + bb + b2f(TE2[m*64 + n]));
            }
        }
    }
    __syncthreads();
    // ---------- phase 7: 1x1 conv -> OT [64][128] (over H) ----------
    {
        for (int i = tid; i < 4096; i += 256){
            int co = i >> 6, ii = i & 63;
            CWs[co*72 + ii] = f2b(cw[i]);
        }
        __syncthreads();
        bfrag ac[2];
        #pragma unroll
        for (int k2=0;k2<2;++k2) ac[k2] = ld_frag(CWs + (w*16)*72 + k2*32, 72);
        int rq = g*4;
        for (int nt = 0; nt < 8; ++nt){
            ffrag accc = fz;
            #pragma unroll
            for (int k2=0;k2<2;++k2){
                bfrag bh = ld_frag(XT + nt*16*72 + k2*32, 72);
                accc = MFMA(ac[k2], bh, accc);
            }
            int tok = nt*16 + c;
            #pragma unroll
            for (int r=0;r<4;++r){
                int co = w*16 + rq + r;
                OT[co*128 + tok] = f2b(accc[r] + b2f(CON[320+co]));
            }
        }
    }
    __syncthreads();
    // ---------- phase 8: out = (1+gamma)*(conv + x) + beta ----------
    {
        int cc = tid >> 2, seg = (tid & 3)*32;
        float gamma = 1.f + gb[b*128 + cc];
        float beta  = gb[b*128 + 64 + cc];
        const size_t gbase = (size_t)b*64*NTOK + (size_t)cc*NTOK + n0 + seg;
        #pragma unroll
        for (int u = 0; u < 8; ++u){
            float cv[4];
            ld4(OT + cc*128 + seg + u*4, cv);
            float4 xv = *(const float4*)(x + gbase + u*4);
            float4 ov;
            ov.x = fmaf(gamma, cv[0]+xv.x, beta);
            ov.y = fmaf(gamma, cv[1]+xv.y, beta);
            ov.z = fmaf(gamma, cv[2]+xv.z, beta);
            ov.w = fmaf(gamma, cv[3]+xv.w, beta);
            *(float4*)(out + gbase + u*4) = ov;
        }
    }
}

extern "C" void kernel_launch(void* const* d_in, const int* in_sizes, int n_in,
                              void* d_out, int out_size, void* d_ws, size_t ws_size,
                              hipStream_t stream){
    const float* x   = (const float*)d_in[0];
    const float* te  = (const float*)d_in[1];
    const float* qw  = (const float*)d_in[2];
    const float* qb  = (const float*)d_in[3];
    const float* kw  = (const float*)d_in[4];
    const float* kb  = (const float*)d_in[5];
    const float* vw  = (const float*)d_in[6];
    const float* vb  = (const float*)d_in[7];
    const float* ow  = (const float*)d_in[8];
    const float* ob  = (const float*)d_in[9];
    const float* ln1w= (const float*)d_in[10];
    const float* ln1b= (const float*)d_in[11];
    const float* ln2w= (const float*)d_in[12];
    const float* ln2b= (const float*)d_in[13];
    const float* w1  = (const float*)d_in[14];
    const float* b1  = (const float*)d_in[15];
    const float* w2  = (const float*)d_in[16];
    const float* b2  = (const float*)d_in[17];
    const float* cw  = (const float*)d_in[18];
    const float* cb  = (const float*)d_in[19];
    const float* m1w = (const float*)d_in[20];
    const float* m1b = (const float*)d_in[21];
    const float* m2w = (const float*)d_in[22];
    const float* m2b = (const float*)d_in[23];

    char* ws = (char*)d_ws;
    const size_t BUF = (size_t)TOTTOK*64*2;       // 16.78 MB per bf16 buffer
    bf16* xT  = (bf16*)(ws);
    bf16* teT = (bf16*)(ws + BUF);
    float* pool = (float*)(ws + 2*BUF);
    float* gbp  = (float*)(ws + 2*BUF + 32768);

    hipMemsetAsync(pool, 0, 8*1024*sizeof(float), stream);
    transpose_kernel<<<2048, 256, 0, stream>>>(x, te, xT, teT, pool);
    film_kernel<<<8, 128, 0, stream>>>(pool, m1w, m1b, m2w, m2b, gbp);
    mega_kernel<<<TOTTOK/128, 256, 0, stream>>>(xT, teT, x,
        qw, kw, vw, qb, kb, vb, ln1w, ln1b, ow, ob, ln2w, ln2b,
        w1, b1, w2, b2, cw, cb, gbp, (float*)d_out);
}